// Round 8
// baseline (8218.307 us; speedup 1.0000x reference)
//
#include <hip/hip_runtime.h>

typedef unsigned int uint;
typedef unsigned short u16;
typedef short s16x8 __attribute__((ext_vector_type(8)));
typedef float f32x4 __attribute__((ext_vector_type(4)));
typedef uint u32x4 __attribute__((ext_vector_type(4)));
typedef uint u32x2 __attribute__((ext_vector_type(2)));

#define MFMA16(a, b, c) __builtin_amdgcn_mfma_f32_16x16x32_bf16((a), (b), (c), 0, 0, 0)

// ---- problem constants ----
// B=64, S=512, D=512, H=512, L=2
// sync region (3072 ints = 12288 B):
//   int[0]              bar L0 (own 128B line)
//   int[32]             bar L1 (own 128B line)
//   int[64..71]         claim L0
//   int[72..79]         claim L1
//   int[80],[81]        winner L0/L1
//   int[256..1279]      release lines L0 (32 lines x 32 ints)
//   int[1280..2303]     release lines L1
static const size_t OFF_SYNC = 0;                      // 12288 B
static const size_t OFF_HB  = 12288;                   // [2 layers][2 bufs][64][512] bf16 = 262144
static const size_t OFF_RHB = 274432;                  // [64][512] bf16 = 65536
static const size_t OFF_WT  = 339968;                  // [2][3][512][1024] bf16 = 6291456
static const size_t OFF_YS0 = 6631424;                 // [64][512][512] bf16 = 33554432
static const size_t OFF_GX  = 40185856;                // [512][64][1536] f32 or bf16
static const size_t GX_ELEMS = (size_t)512 * 64 * 1536;

__device__ __forceinline__ short f2bf(float x) {       // RNE float->bf16
  uint u = __builtin_bit_cast(uint, x);
  u = u + 0x7fffu + ((u >> 16) & 1u);
  return (short)(u >> 16);
}
__device__ __forceinline__ float bf2f(u16 v) {
  uint u = ((uint)v) << 16;
  return __builtin_bit_cast(float, u);
}

// ---- raw memory ops (plain scope: L1 + XCD-L2; co-located workers share the L2) ----
__device__ __forceinline__ u32x4 ld16(const void* p) {
  u32x4 r;
  asm volatile("global_load_dwordx4 %0, %1, off" : "=v"(r) : "v"(p));
  return r;
}
__device__ __forceinline__ u32x2 ld8(const void* p) {
  u32x2 r;
  asm volatile("global_load_dwordx2 %0, %1, off" : "=v"(r) : "v"(p));
  return r;
}
__device__ __forceinline__ void st16(void* p, u32x4 v) {
  asm volatile("global_store_dwordx4 %0, %1, off" :: "v"(p), "v"(v));
}
__device__ __forceinline__ void st8(void* p, u32x2 v) {
  asm volatile("global_store_dwordx2 %0, %1, off" :: "v"(p), "v"(v));
}
__device__ __forceinline__ void waitv0() {
  asm volatile("s_waitcnt vmcnt(0)" ::: "memory");
  __builtin_amdgcn_sched_barrier(0);   // rule #18
}

// ---------------- sentinel ----------------
__global__ void sentinel_kernel(float* __restrict__ out, float v) {
  out[threadIdx.x] = v;
}

// ---------------- init: sync words, h0 -> bf16 ----------------
__global__ void init_kernel(const float* __restrict__ h_in, u16* __restrict__ hb,
                            int* __restrict__ sync) {
  int idx = blockIdx.x * 256 + threadIdx.x;
  if (idx < 3072) sync[idx] = (idx == 80 || idx == 81) ? -1 : 0;   // winners = -1
  for (int i = idx; i < 2 * 64 * 512; i += gridDim.x * 256) {
    int l = i >> 15, b = (i >> 9) & 63, c = i & 511;
    hb[l * 65536 + b * 512 + c] = (u16)f2bf(h_in[(b * 2 + l) * 512 + c]);
  }
}

// ---------------- W (L,1024,512) f32 -> WT[l][g][n][k] bf16 (k-major) ----------------
__global__ void convert_w_kernel(const float* __restrict__ Wr, const float* __restrict__ Wz,
                                 const float* __restrict__ Wh, u16* __restrict__ WT) {
  int idx = blockIdx.x * 256 + threadIdx.x;       // 6*512*1024 = 3145728 total
  int n = idx & 511, k = (idx >> 9) & 1023, lg = idx >> 19;
  int l = (lg >= 3) ? 1 : 0, g = lg - l * 3;
  const float* W = (g == 0 ? Wr : (g == 1 ? Wz : Wh)) + (size_t)l * 1024 * 512;
  WT[((size_t)lg * 512 + n) * 1024 + k] = (u16)f2bf(W[k * 512 + n]);
}

// ---------------- input projection GEMM: gx[s][b][g*512+n] = A @ WT_g + bias ----------------
template <int AF32, int GXBF>
__global__ __launch_bounds__(256) void proj_kernel(
    const void* __restrict__ Araw, const u16* __restrict__ WT,
    const float* __restrict__ br, const float* __restrict__ bz, const float* __restrict__ bh,
    void* __restrict__ gx) {
  __shared__ u16 Alds[128 * 64];
  __shared__ u16 Blds[128 * 64];
  const int tid = threadIdx.x;
  const int wave = tid >> 6, lane = tid & 63;
  const int lan15 = lane & 15, lanhi = lane >> 4;
  const int mb = blockIdx.x & 255, nb = blockIdx.x >> 8;
  const int m0 = mb * 128, n0 = nb * 128;
  const int wm = (wave >> 1) * 64, wn = (wave & 1) * 64;

  const f32x4 z4 = {0.f, 0.f, 0.f, 0.f};
  f32x4 acc[4][4];
#pragma unroll
  for (int i = 0; i < 4; ++i)
#pragma unroll
    for (int j = 0; j < 4; ++j) acc[i][j] = z4;

  for (int kb = 0; kb < 512; kb += 64) {
    __syncthreads();
    if constexpr (AF32) {
      const float* A = (const float*)Araw;
#pragma unroll
      for (int p = 0; p < 4; ++p) {        // stage+convert A tile 128x64 (XOR-swizzled 16B slots)
        int idx = p * 256 + tid;
        int row = idx >> 3, slot = idx & 7;
        const float* src = A + (size_t)(m0 + row) * 512 + kb + slot * 8;
        float4 v0 = *(const float4*)src;
        float4 v1 = *(const float4*)(src + 4);
        u16 tmp[8] = {(u16)f2bf(v0.x), (u16)f2bf(v0.y), (u16)f2bf(v0.z), (u16)f2bf(v0.w),
                      (u16)f2bf(v1.x), (u16)f2bf(v1.y), (u16)f2bf(v1.z), (u16)f2bf(v1.w)};
        *(uint4*)((char*)Alds + row * 128 + ((slot ^ (row & 7)) * 16)) = *(uint4*)tmp;
      }
    } else {
      const u16* A = (const u16*)Araw;
#pragma unroll
      for (int p = 0; p < 4; ++p) {
        int idx = p * 256 + tid;
        int row = idx >> 3, slot = idx & 7;
        uint4 v = *(const uint4*)(A + (size_t)(m0 + row) * 512 + kb + slot * 8);
        *(uint4*)((char*)Alds + row * 128 + ((slot ^ (row & 7)) * 16)) = v;
      }
    }
#pragma unroll
    for (int p = 0; p < 4; ++p) {          // stage B tile 128x64 from WT (n-major rows)
      int idx = p * 256 + tid;
      int row = idx >> 3, slot = idx & 7;
      int ng = n0 + row, g = ng >> 9, nc = ng & 511;
      uint4 v = *(const uint4*)(WT + ((size_t)g * 512 + nc) * 1024 + kb + slot * 8);
      *(uint4*)((char*)Blds + row * 128 + ((slot ^ (row & 7)) * 16)) = v;
    }
    __syncthreads();
#pragma unroll
    for (int ks = 0; ks < 2; ++ks) {
      s16x8 af[4], bfr[4];
#pragma unroll
      for (int f = 0; f < 4; ++f) {
        int rowA = wm + f * 16 + lan15;
        af[f] = *(const s16x8*)((const char*)Alds + rowA * 128 + (((ks * 4 + lanhi) ^ (rowA & 7)) * 16));
        int rowB = wn + f * 16 + lan15;
        bfr[f] = *(const s16x8*)((const char*)Blds + rowB * 128 + (((ks * 4 + lanhi) ^ (rowB & 7)) * 16));
      }
#pragma unroll
      for (int mf = 0; mf < 4; ++mf)
#pragma unroll
        for (int nf = 0; nf < 4; ++nf)
          acc[mf][nf] = MFMA16(af[mf], bfr[nf], acc[mf][nf]);
    }
  }
#pragma unroll
  for (int nf = 0; nf < 4; ++nf) {
    int n = n0 + wn + nf * 16 + lan15;
    int g = n >> 9, nc = n & 511;
    float bias = (g == 0 ? br[nc] : (g == 1 ? bz[nc] : bh[nc]));
#pragma unroll
    for (int mf = 0; mf < 4; ++mf) {
#pragma unroll
      for (int q = 0; q < 4; ++q) {
        int m = m0 + wm + mf * 16 + lanhi * 4 + q;
        int s = m & 511, b = m >> 9;
        size_t e = (size_t)(s * 64 + b) * 1536 + n;
        float v = acc[mf][nf][q] + bias;
        if constexpr (GXBF) ((u16*)gx)[e] = (u16)f2bf(v);
        else ((float*)gx)[e] = v;
      }
    }
  }
}

// ---------------- master-release XCD-local barrier ----------------
// Arrive: fire-and-forget atomic_add(1) to bar (no arriver ever polls it).
// Master (slot 0): polls bar (single poller, no contention) to 32*p, then broadcasts
// epoch p to 32 per-WG release lines (128B apart).
// Others: poll ONLY their own release line via atomic_add(0) sc0 (one poller per line).
__device__ __forceinline__ void mbar(int* bar, int* rel, int p, int slot) {
  asm volatile("s_waitcnt vmcnt(0)" ::: "memory");   // my exchange stores are in L2
  __syncthreads();                                   // whole WG's stores are in L2
  if (threadIdx.x == 0) {
    int one = 1;
    asm volatile("global_atomic_add %0, %1, off" :: "v"(bar), "v"(one) : "memory");
    if (slot == 0) {
      int v, zero = 0, iter = 0;
      const int want = 32 * p;
      do {
        __builtin_amdgcn_s_sleep(1);
        asm volatile("global_atomic_add %0, %1, %2, off sc0\n\ts_waitcnt vmcnt(0)"
                     : "=v"(v) : "v"(bar), "v"(zero) : "memory");
      } while (v < want && ++iter < (1 << 17));      // watchdog: fail wrong, not hung
      for (int i = 0; i < 32; ++i) {                 // broadcast release epoch
        int pv = p;
        asm volatile("global_store_dword %0, %1, off" :: "v"(rel + i * 32), "v"(pv) : "memory");
      }
    } else {
      int* myrel = rel + slot * 32;
      int v, zero = 0, iter = 0;
      do {
        __builtin_amdgcn_s_sleep(1);
        asm volatile("global_atomic_add %0, %1, %2, off sc0\n\ts_waitcnt vmcnt(0)"
                     : "=v"(v) : "v"(myrel), "v"(zero) : "memory");
      } while (v < p && ++iter < (1 << 17));         // watchdog
    }
  }
  __syncthreads();
  __builtin_amdgcn_sched_barrier(0);
}

// red buffer: [4 waves][32 cols][64 batches] f32, 16B-slot XOR swizzle on batch
__device__ __forceinline__ int red_off32(int w, int c, int b) {
  return ((w * 32 + c) << 6) + ((((b >> 2) ^ (c & 15)) & 15) << 2) + (b & 3);
}

template <int GXBF>
__device__ __forceinline__ void unpack4(const u32x4& a4, const u32x2& a2, float o[4]) {
  if constexpr (GXBF) {
    const u16* p = (const u16*)&a2;
#pragma unroll
    for (int i = 0; i < 4; ++i) o[i] = bf2f(p[i]);
  } else {
    const float* p = (const float*)&a4;
#pragma unroll
    for (int i = 0; i < 4; ++i) o[i] = p[i];
  }
}

// ---------------- persistent recurrent kernel ----------------
// grid=256, 84KB LDS -> exactly 1 WG/CU -> every XCD hosts exactly 32 WGs.
// Election: first 32 claimants of the winning XCD become workers (one full XCD).
template <int GXBF>
__global__ __launch_bounds__(256, 1) void recur_kernel(
    const void* __restrict__ gx,     // [512][64][1536] f32 or bf16
    const u16* __restrict__ WT,      // layer base [3][512][1024], recurrent part k in [512,1024)
    const float* __restrict__ h_in,  // [64][2][512]
    u16* __restrict__ hb,            // [2][64][512] bf16 double buffer (this layer)
    u16* __restrict__ rhb,           // [64][512] bf16
    u16* __restrict__ out_bf,        // layer0: ys0 [b][t][c]
    float* __restrict__ out_f32,     // layer1: d_out [b][t][c]
    float* __restrict__ finals,      // d_out + B*S*H, [b][l][c]
    const int layer, int* __restrict__ bar, int* __restrict__ rel,
    int* __restrict__ claim, int* __restrict__ winner) {
  __shared__ float red[21504];       // 84 KiB: forces 1 WG/CU
  __shared__ int s_slot;

  if (threadIdx.x == 0) {
    int xcc;
    asm volatile("s_getreg_b32 %0, hwreg(HW_REG_XCC_ID)" : "=s"(xcc));
    xcc &= 7;
    int slot = __hip_atomic_fetch_add(&claim[xcc], 1, __ATOMIC_RELAXED, __HIP_MEMORY_SCOPE_AGENT);
    int my = -1;
    if (slot < 32) {
      if (slot == 31) {
        int expected = -1;
        __hip_atomic_compare_exchange_strong(winner, &expected, xcc, __ATOMIC_RELAXED,
                                             __ATOMIC_RELAXED, __HIP_MEMORY_SCOPE_AGENT);
      }
      int w, it = 0;
      do {
        __builtin_amdgcn_s_sleep(8);
        w = __hip_atomic_load(winner, __ATOMIC_RELAXED, __HIP_MEMORY_SCOPE_AGENT);
      } while (w < 0 && ++it < (1 << 22));   // watchdog
      my = (w == xcc) ? slot : -1;
    }
    s_slot = my;
  }
  __syncthreads();
  const int slot = s_slot;
  if (slot < 0) return;

  const int tid = threadIdx.x;
  const int wave = tid >> 6, lane = tid & 63;
  const int lan15 = lane & 15, lanhi = lane >> 4;
  const int c0 = slot * 16;           // owned h-columns [c0, c0+16)
  const int kw = wave * 128;          // K-split per wave
  const int ke8 = lanhi * 8;
  const int ES = GXBF ? 2 : 4;

  // recurrent-weight fragments -> registers (one-time): 16 cols per gate
  s16x8 wrz[2][4];   // [gate r/z][kstep]
  s16x8 whh[4];
#pragma unroll
  for (int g = 0; g < 2; ++g)
#pragma unroll
    for (int ks = 0; ks < 4; ++ks)
      wrz[g][ks] = *(const s16x8*)(WT + ((size_t)(g * 512 + c0 + lan15)) * 1024 + 512 + kw + ks * 32 + ke8);
#pragma unroll
  for (int ks = 0; ks < 4; ++ks)
    whh[ks] = *(const s16x8*)(WT + ((size_t)(1024 + c0 + lan15)) * 1024 + 512 + kw + ks * 32 + ke8);

  // fp32 h state: thread owns batch ob, 4 cols at c0+oc
  const int ob = tid >> 2, oc = (tid & 3) * 4;
  float hown[4];
#pragma unroll
  for (int i = 0; i < 4; ++i) hown[i] = h_in[(ob * 2 + layer) * 512 + c0 + oc + i];

  // gx prefetch (double-buffered register sets A/B; 2 steps per loop iteration)
  u32x4 pfA_r4 = {0,0,0,0}, pfA_z4 = {0,0,0,0}, pfA_h4 = {0,0,0,0};
  u32x2 pfA_r2 = {0,0}, pfA_z2 = {0,0}, pfA_h2 = {0,0};
  u32x4 pfB_r4 = {0,0,0,0}, pfB_z4 = {0,0,0,0}, pfB_h4 = {0,0,0,0};
  u32x2 pfB_r2 = {0,0}, pfB_z2 = {0,0}, pfB_h2 = {0,0};

#define ISSUE_PF(SET, TP)                                                            \
  {                                                                                  \
    const char* gq = (const char*)gx + ((size_t)((TP) * 64 + ob) * 1536 + c0 + oc) * ES; \
    if constexpr (GXBF) {                                                            \
      pf##SET##_r2 = ld8(gq);                                                        \
      pf##SET##_z2 = ld8(gq + 1024);                                                 \
      pf##SET##_h2 = ld8(gq + 2048);                                                 \
    } else {                                                                         \
      pf##SET##_r4 = ld16(gq);                                                       \
      pf##SET##_z4 = ld16(gq + 2048);                                                \
      pf##SET##_h4 = ld16(gq + 4096);                                                \
    }                                                                                \
  }

  ISSUE_PF(A, 0);   // prologue: gx(0) in flight (drained by waitv0 in step 0 phase 1)
  waitv0();

  const f32x4 z4 = {0.f, 0.f, 0.f, 0.f};
  int p = 0;

#define STEP_BODY(T, CUR, NXT)                                                       \
  {                                                                                  \
    const u16* hc = hb + ((T) & 1) * (64 * 512);                                     \
    /* phase 1: hl loads, then prefetch gx(T+1) into NXT */                          \
    u32x4 hl[4][4];                                                                  \
    _Pragma("unroll")                                                                \
    for (int ks = 0; ks < 4; ++ks)                                                   \
      _Pragma("unroll")                                                              \
      for (int mf = 0; mf < 4; ++mf)                                                 \
        hl[ks][mf] = ld16(hc + (mf * 16 + lan15) * 512 + kw + ks * 32 + ke8);        \
    ISSUE_PF(NXT, (T) < 511 ? (T) + 1 : 511);                                        \
    asm volatile("s_waitcnt vmcnt(3)" ::: "memory");  /* hl done, pf in flight */    \
    __builtin_amdgcn_sched_barrier(0);                                               \
    f32x4 acc[4][2];                                                                 \
    _Pragma("unroll")                                                                \
    for (int i = 0; i < 4; ++i) { acc[i][0] = z4; acc[i][1] = z4; }                  \
    _Pragma("unroll")                                                                \
    for (int ks = 0; ks < 4; ++ks) {                                                 \
      _Pragma("unroll")                                                              \
      for (int mf = 0; mf < 4; ++mf) {                                               \
        s16x8 af = __builtin_bit_cast(s16x8, hl[ks][mf]);                            \
        acc[mf][0] = MFMA16(af, wrz[0][ks], acc[mf][0]);                             \
        acc[mf][1] = MFMA16(af, wrz[1][ks], acc[mf][1]);                             \
      }                                                                              \
    }                                                                                \
    _Pragma("unroll")                                                                \
    for (int mf = 0; mf < 4; ++mf)                                                   \
      _Pragma("unroll")                                                              \
      for (int g = 0; g < 2; ++g)                                                    \
        *(f32x4*)(red + red_off32(wave, g * 16 + lan15, mf * 16 + lanhi * 4)) = acc[mf][g]; \
    __syncthreads();                                                                 \
    float zg[4];                                                                     \
    {                                                                                \
      float grf[4], gzf[4];                                                          \
      unpack4<GXBF>(pf##CUR##_r4, pf##CUR##_r2, grf);                                \
      unpack4<GXBF>(pf##CUR##_z4, pf##CUR##_z2, gzf);                                \
      u16 rh[4];                                                                     \
      _Pragma("unroll")                                                              \
      for (int i = 0; i < 4; ++i) {                                                  \
        float rp = grf[i], zp = gzf[i];                                              \
        _Pragma("unroll")                                                            \
        for (int w = 0; w < 4; ++w) {                                                \
          rp += red[red_off32(w, oc + i, ob)];                                       \
          zp += red[red_off32(w, 16 + oc + i, ob)];                                  \
        }                                                                            \
        float r = 1.f / (1.f + __expf(-rp));                                         \
        zg[i] = 1.f / (1.f + __expf(-zp));                                           \
        rh[i] = (u16)f2bf(r * hown[i]);                                              \
      }                                                                              \
      st8(rhb + ob * 512 + c0 + oc, __builtin_bit_cast(u32x2, rh));                  \
    }                                                                                \
    ++p; mbar(bar, rel, p, slot);                                                    \
    /* phase 2 */                                                                    \
    u32x4 rl[4][4];                                                                  \
    _Pragma("unroll")                                                                \
    for (int ks = 0; ks < 4; ++ks)                                                   \
      _Pragma("unroll")                                                              \
      for (int mf = 0; mf < 4; ++mf)                                                 \
        rl[ks][mf] = ld16(rhb + (mf * 16 + lan15) * 512 + kw + ks * 32 + ke8);       \
    waitv0();                                                                        \
    f32x4 acc2[4];                                                                   \
    _Pragma("unroll")                                                                \
    for (int i = 0; i < 4; ++i) acc2[i] = z4;                                        \
    _Pragma("unroll")                                                                \
    for (int ks = 0; ks < 4; ++ks)                                                   \
      _Pragma("unroll")                                                              \
      for (int mf = 0; mf < 4; ++mf)                                                 \
        acc2[mf] = MFMA16(__builtin_bit_cast(s16x8, rl[ks][mf]), whh[ks], acc2[mf]); \
    _Pragma("unroll")                                                                \
    for (int mf = 0; mf < 4; ++mf)                                                   \
      *(f32x4*)(red + red_off32(wave, lan15, mf * 16 + lanhi * 4)) = acc2[mf];       \
    __syncthreads();                                                                 \
    float hn[4];                                                                     \
    u16 hv[4];                                                                       \
    {                                                                                \
      float ghf[4];                                                                  \
      unpack4<GXBF>(pf##CUR##_h4, pf##CUR##_h2, ghf);                                \
      _Pragma("unroll")                                                              \
      for (int i = 0; i < 4; ++i) {                                                  \
        float wp = 0.f;                                                              \
        _Pragma("unroll")                                                            \
        for (int w = 0; w < 4; ++w) wp += red[red_off32(w, oc + i, ob)];             \
        float pre = ghf[i] + wp;                                                     \
        pre = fminf(15.f, fmaxf(-15.f, pre));                                        \
        float e = __expf(-2.f * pre);                                                \
        float ht = (1.f - e) / (1.f + e);                                            \
        hn[i] = (1.f - zg[i]) * hown[i] + zg[i] * ht;                                \
        hown[i] = hn[i];                                                             \
        hv[i] = (u16)f2bf(hn[i]);                                                    \
      }                                                                              \
      st8(hb + (((T) & 1) ^ 1) * (64 * 512) + ob * 512 + c0 + oc,                    \
          __builtin_bit_cast(u32x2, hv));                                            \
    }                                                                                \
    ++p;                                                                             \
    if ((T) != 511) mbar(bar, rel, p, slot);                                         \
    if (layer == 0) {                                                                \
      st8(out_bf + ((size_t)ob * 512 + (T)) * 512 + c0 + oc,                         \
          __builtin_bit_cast(u32x2, hv));                                            \
    } else {                                                                         \
      f32x4 o = {hn[0], hn[1], hn[2], hn[3]};                                        \
      st16(out_f32 + ((size_t)ob * 512 + (T)) * 512 + c0 + oc,                       \
           __builtin_bit_cast(u32x4, o));                                            \
    }                                                                                \
    if ((T) == 511) {                                                                \
      float* f = finals + (size_t)(ob * 2 + layer) * 512 + c0 + oc;                  \
      _Pragma("unroll")                                                              \
      for (int i = 0; i < 4; ++i) f[i] = hn[i];                                      \
    }                                                                                \
  }

  for (int tt = 0; tt < 512; tt += 2) {
    STEP_BODY(tt, A, B);
    STEP_BODY(tt + 1, B, A);
  }
#undef STEP_BODY
#undef ISSUE_PF
}

template <int GXBF>
static void run_all(const float* x, const float* h, const float* Wr, const float* br,
                    const float* Wz, const float* bz, const float* Wh, const float* bh,
                    float* out, char* ws, hipStream_t stream) {
  int* sync   = (int*)(ws + OFF_SYNC);
  int* bar0   = sync + 0;      // own 128B line
  int* bar1   = sync + 32;     // own 128B line
  int* claim0 = sync + 64;
  int* claim1 = sync + 72;
  int* winner = sync + 80;     // [80],[81]
  int* rel0   = sync + 256;    // 32 lines x 128B
  int* rel1   = sync + 1280;
  u16* hbAll = (u16*)(ws + OFF_HB);
  u16* rhb   = (u16*)(ws + OFF_RHB);
  u16* WT    = (u16*)(ws + OFF_WT);
  u16* ys0   = (u16*)(ws + OFF_YS0);
  void* gx   = (void*)(ws + OFF_GX);
  float* finals = out + 16777216;

  init_kernel<<<64, 256, 0, stream>>>(h, hbAll, sync);
  convert_w_kernel<<<12288, 256, 0, stream>>>(Wr, Wz, Wh, WT);

  // layer 0 (A = x, f32)
  proj_kernel<1, GXBF><<<3072, 256, 0, stream>>>(x, WT, br, bz, bh, gx);
  recur_kernel<GXBF><<<256, 256, 0, stream>>>(gx, WT, h, hbAll, rhb, ys0, nullptr, finals, 0,
                                              bar0, rel0, claim0, winner + 0);
  // layer 1 (A = ys0, bf16)
  proj_kernel<0, GXBF><<<3072, 256, 0, stream>>>(ys0, WT + (size_t)3 * 512 * 1024,
                                                 br + 512, bz + 512, bh + 512, gx);
  recur_kernel<GXBF><<<256, 256, 0, stream>>>(gx, WT + (size_t)3 * 512 * 1024, h, hbAll + 65536, rhb,
                                              nullptr, out, finals, 1,
                                              bar1, rel1, claim1, winner + 1);
}

extern "C" void kernel_launch(void* const* d_in, const int* in_sizes, int n_in,
                              void* d_out, int out_size, void* d_ws, size_t ws_size,
                              hipStream_t stream) {
  const float* x  = (const float*)d_in[0];
  const float* h  = (const float*)d_in[1];
  const float* Wr = (const float*)d_in[2];
  const float* br = (const float*)d_in[3];
  const float* Wz = (const float*)d_in[4];
  const float* bz = (const float*)d_in[5];
  const float* Wh = (const float*)d_in[6];
  const float* bh = (const float*)d_in[7];
  float* out = (float*)d_out;
  char* ws = (char*)d_ws;

  const size_t need_f32 = OFF_GX + GX_ELEMS * 4;   // 241,512,448 B (230.3 MiB)
  const size_t need_bf  = OFF_GX + GX_ELEMS * 2;   // 140,849,152 B (134.3 MiB)

  if (ws_size >= need_f32) {
    run_all<0>(x, h, Wr, br, Wz, bz, Wh, bh, out, ws, stream);
  } else if (ws_size >= need_bf) {
    run_all<1>(x, h, Wr, br, Wz, bz, Wh, bh, out, ws, stream);
  } else {
    sentinel_kernel<<<1, 64, 0, stream>>>(out, (float)ws_size);
  }
}

// Round 9
// 6223.545 us; speedup vs baseline: 1.3205x; 1.3205x over previous
//
#include <hip/hip_runtime.h>

typedef unsigned int uint;
typedef unsigned short u16;
typedef short s16x8 __attribute__((ext_vector_type(8)));
typedef float f32x4 __attribute__((ext_vector_type(4)));
typedef uint u32x4 __attribute__((ext_vector_type(4)));
typedef uint u32x2 __attribute__((ext_vector_type(2)));

#define MFMA16(a, b, c) __builtin_amdgcn_mfma_f32_16x16x32_bf16((a), (b), (c), 0, 0, 0)

// ---- problem constants ----
// B=64, S=512, D=512, H=512, L=2
// sync region (256 ints = 1024 B):
//   [0] bar0 (own 128B line)  [32] bar1 (own 128B line)
//   [64..71] claim (per-XCD)  [80] winner0  [81] winner1  (L3-scope agent atomics)
//   [96] prog0 (own 128B line, L3-scope agent atomics)
static const size_t OFF_SYNC = 0;                      // 1024 B
static const size_t OFF_HB   = 1024;                   // [2 layers][2 bufs][64][512] bf16 = 262144
static const size_t OFF_RHB0 = 263168;                 // [64][512] bf16 = 65536
static const size_t OFF_RHB1 = 328704;                 // [64][512] bf16 = 65536
static const size_t OFF_WT   = 394240;                 // [2][3][512][1024] bf16 = 6291456
static const size_t OFF_YS0  = 6685696;                // [64][512][512] bf16 = 33554432
static const size_t OFF_GX   = 40240128;               // [512][64][1536] f32 or bf16 (layer 0 only)
static const size_t GX_ELEMS = (size_t)512 * 64 * 1536;

__device__ __forceinline__ short f2bf(float x) {       // RNE float->bf16
  uint u = __builtin_bit_cast(uint, x);
  u = u + 0x7fffu + ((u >> 16) & 1u);
  return (short)(u >> 16);
}
__device__ __forceinline__ float bf2f(u16 v) {
  uint u = ((uint)v) << 16;
  return __builtin_bit_cast(float, u);
}

// ---- raw memory ops ----
__device__ __forceinline__ u32x4 ld16(const void* p) {          // plain: L1 + local L2
  u32x4 r;
  asm volatile("global_load_dwordx4 %0, %1, off" : "=v"(r) : "v"(p));
  return r;
}
__device__ __forceinline__ u32x2 ld8(const void* p) {
  u32x2 r;
  asm volatile("global_load_dwordx2 %0, %1, off" : "=v"(r) : "v"(p));
  return r;
}
__device__ __forceinline__ void st16(void* p, u32x4 v) {
  asm volatile("global_store_dwordx4 %0, %1, off" :: "v"(p), "v"(v));
}
__device__ __forceinline__ void st8(void* p, u32x2 v) {
  asm volatile("global_store_dwordx2 %0, %1, off" :: "v"(p), "v"(v));
}
// cross-XCD coherent (system scope, served at L3): sc0 sc1 — R3-proven combo
__device__ __forceinline__ u32x4 ld16c(const void* p) {
  u32x4 r;
  asm volatile("global_load_dwordx4 %0, %1, off sc0 sc1" : "=v"(r) : "v"(p));
  return r;
}
__device__ __forceinline__ void st8c(void* p, u32x2 v) {
  asm volatile("global_store_dwordx2 %0, %1, off sc0 sc1" :: "v"(p), "v"(v));
}
__device__ __forceinline__ void waitv0() {
  asm volatile("s_waitcnt vmcnt(0)" ::: "memory");
  __builtin_amdgcn_sched_barrier(0);   // rule #18
}

// ---------------- sentinel ----------------
__global__ void sentinel_kernel(float* __restrict__ out, float v) {
  out[threadIdx.x] = v;
}

// ---------------- init: sync words, h0 -> bf16 ----------------
__global__ void init_kernel(const float* __restrict__ h_in, u16* __restrict__ hb,
                            int* __restrict__ sync) {
  int idx = blockIdx.x * 256 + threadIdx.x;
  if (idx < 256) sync[idx] = (idx == 80 || idx == 81) ? -1 : 0;   // winners = -1
  for (int i = idx; i < 2 * 64 * 512; i += gridDim.x * 256) {
    int l = i >> 15, b = (i >> 9) & 63, c = i & 511;
    hb[l * 65536 + b * 512 + c] = (u16)f2bf(h_in[(b * 2 + l) * 512 + c]);
  }
}

// ---------------- W (L,1024,512) f32 -> WT[l][g][n][k] bf16 (k-major) ----------------
__global__ void convert_w_kernel(const float* __restrict__ Wr, const float* __restrict__ Wz,
                                 const float* __restrict__ Wh, u16* __restrict__ WT) {
  int idx = blockIdx.x * 256 + threadIdx.x;       // 6*512*1024 = 3145728 total
  int n = idx & 511, k = (idx >> 9) & 1023, lg = idx >> 19;
  int l = (lg >= 3) ? 1 : 0, g = lg - l * 3;
  const float* W = (g == 0 ? Wr : (g == 1 ? Wz : Wh)) + (size_t)l * 1024 * 512;
  WT[((size_t)lg * 512 + n) * 1024 + k] = (u16)f2bf(W[k * 512 + n]);
}

// ---------------- input projection GEMM (layer 0 only) ----------------
template <int GXBF>
__global__ __launch_bounds__(256) void proj_kernel(
    const float* __restrict__ A, const u16* __restrict__ WT,
    const float* __restrict__ br, const float* __restrict__ bz, const float* __restrict__ bh,
    void* __restrict__ gx) {
  __shared__ u16 Alds[128 * 64];
  __shared__ u16 Blds[128 * 64];
  const int tid = threadIdx.x;
  const int wave = tid >> 6, lane = tid & 63;
  const int lan15 = lane & 15, lanhi = lane >> 4;
  const int mb = blockIdx.x & 255, nb = blockIdx.x >> 8;
  const int m0 = mb * 128, n0 = nb * 128;
  const int wm = (wave >> 1) * 64, wn = (wave & 1) * 64;

  const f32x4 z4 = {0.f, 0.f, 0.f, 0.f};
  f32x4 acc[4][4];
#pragma unroll
  for (int i = 0; i < 4; ++i)
#pragma unroll
    for (int j = 0; j < 4; ++j) acc[i][j] = z4;

  for (int kb = 0; kb < 512; kb += 64) {
    __syncthreads();
#pragma unroll
    for (int p = 0; p < 4; ++p) {        // stage+convert A tile 128x64 (XOR-swizzled 16B slots)
      int idx = p * 256 + tid;
      int row = idx >> 3, slot = idx & 7;
      const float* src = A + (size_t)(m0 + row) * 512 + kb + slot * 8;
      float4 v0 = *(const float4*)src;
      float4 v1 = *(const float4*)(src + 4);
      u16 tmp[8] = {(u16)f2bf(v0.x), (u16)f2bf(v0.y), (u16)f2bf(v0.z), (u16)f2bf(v0.w),
                    (u16)f2bf(v1.x), (u16)f2bf(v1.y), (u16)f2bf(v1.z), (u16)f2bf(v1.w)};
      *(uint4*)((char*)Alds + row * 128 + ((slot ^ (row & 7)) * 16)) = *(uint4*)tmp;
    }
#pragma unroll
    for (int p = 0; p < 4; ++p) {        // stage B tile 128x64 from WT (n-major rows)
      int idx = p * 256 + tid;
      int row = idx >> 3, slot = idx & 7;
      int ng = n0 + row, g = ng >> 9, nc = ng & 511;
      uint4 v = *(const uint4*)(WT + ((size_t)g * 512 + nc) * 1024 + kb + slot * 8);
      *(uint4*)((char*)Blds + row * 128 + ((slot ^ (row & 7)) * 16)) = v;
    }
    __syncthreads();
#pragma unroll
    for (int ks = 0; ks < 2; ++ks) {
      s16x8 af[4], bfr[4];
#pragma unroll
      for (int f = 0; f < 4; ++f) {
        int rowA = wm + f * 16 + lan15;
        af[f] = *(const s16x8*)((const char*)Alds + rowA * 128 + (((ks * 4 + lanhi) ^ (rowA & 7)) * 16));
        int rowB = wn + f * 16 + lan15;
        bfr[f] = *(const s16x8*)((const char*)Blds + rowB * 128 + (((ks * 4 + lanhi) ^ (rowB & 7)) * 16));
      }
#pragma unroll
      for (int mf = 0; mf < 4; ++mf)
#pragma unroll
        for (int nf = 0; nf < 4; ++nf)
          acc[mf][nf] = MFMA16(af[mf], bfr[nf], acc[mf][nf]);
    }
  }
#pragma unroll
  for (int nf = 0; nf < 4; ++nf) {
    int n = n0 + wn + nf * 16 + lan15;
    int g = n >> 9, nc = n & 511;
    float bias = (g == 0 ? br[nc] : (g == 1 ? bz[nc] : bh[nc]));
#pragma unroll
    for (int mf = 0; mf < 4; ++mf) {
#pragma unroll
      for (int q = 0; q < 4; ++q) {
        int m = m0 + wm + mf * 16 + lanhi * 4 + q;
        int s = m & 511, b = m >> 9;
        size_t e = (size_t)(s * 64 + b) * 1536 + n;
        float v = acc[mf][nf][q] + bias;
        if constexpr (GXBF) ((u16*)gx)[e] = (u16)f2bf(v);
        else ((float*)gx)[e] = v;
      }
    }
  }
}

// ---------------- XCD-local barrier: L2-executed atomics (R6/R7-proven) ----------------
__device__ __forceinline__ void gbarA(int* bar, int target) {
  asm volatile("s_waitcnt vmcnt(0)" ::: "memory");
  __syncthreads();
  if (threadIdx.x == 0) {
    int one = 1;
    asm volatile("global_atomic_add %0, %1, off" :: "v"(bar), "v"(one) : "memory");
    int v, zero = 0, iter = 0;
    do {
      __builtin_amdgcn_s_sleep(1);
      asm volatile("global_atomic_add %0, %1, %2, off sc0\n\ts_waitcnt vmcnt(0)"
                   : "=v"(v) : "v"(bar), "v"(zero) : "memory");
    } while (v < target && ++iter < (1 << 17));      // watchdog
  }
  __syncthreads();
  __builtin_amdgcn_sched_barrier(0);
}

// red buffer: [4 waves][32 cols][64 batches] f32, 16B-slot XOR swizzle on batch
__device__ __forceinline__ int red_off32(int w, int c, int b) {
  return ((w * 32 + c) << 6) + ((((b >> 2) ^ (c & 15)) & 15) << 2) + (b & 3);
}

template <int GXBF>
__device__ __forceinline__ void unpack4(const u32x4& a4, const u32x2& a2, float o[4]) {
  if constexpr (GXBF) {
    const u16* p = (const u16*)&a2;
#pragma unroll
    for (int i = 0; i < 4; ++i) o[i] = bf2f(p[i]);
  } else {
    const float* p = (const float*)&a4;
#pragma unroll
    for (int i = 0; i < 4; ++i) o[i] = p[i];
  }
}

// ---------------- persistent pipelined GRU: both layers concurrently ----------------
// grid=256, 84KB LDS -> 1 WG/CU -> each XCD hosts exactly 32 WGs.
// Elect TWO XCDs: winner0 runs layer 0 (R7 loop + sc1 ys0 publish + L3 progress counter),
// winner1 runs layer 1 with FUSED input projection, consuming ys0(t) after prog >= t+1.
template <int GXBF>
__global__ __launch_bounds__(256, 1) void gru_pipe(
    const void* __restrict__ gx,     // [512][64][1536] layer-0 gates
    const u16* __restrict__ WT,      // [2][3][512][1024]
    const float* __restrict__ h_in,  // [64][2][512]
    u16* __restrict__ hb,            // [2 layers][2 bufs][64][512]
    u16* __restrict__ rhb0, u16* __restrict__ rhb1,
    u16* __restrict__ ys0,           // [64][512][512] bf16 (L0 -> L1 handoff via L3)
    const float* __restrict__ br, const float* __restrict__ bz, const float* __restrict__ bh,
    float* __restrict__ out_f32,     // d_out [64][512][512] f32
    float* __restrict__ finals,      // d_out + B*S*H  [64][2][512]
    int* __restrict__ sync) {
  __shared__ float red[21504];       // 84 KiB: forces 1 WG/CU
  __shared__ int s_slot, s_role;

  int* bar0 = sync + 0;
  int* bar1 = sync + 32;
  int* claim = sync + 64;
  int* winner0 = sync + 80;
  int* winner1 = sync + 81;
  int* prog = sync + 96;

  // ---- election: two winner XCDs ----
  if (threadIdx.x == 0) {
    int xcc;
    asm volatile("s_getreg_b32 %0, hwreg(HW_REG_XCC_ID)" : "=s"(xcc));
    xcc &= 7;
    int slot = __hip_atomic_fetch_add(&claim[xcc], 1, __ATOMIC_RELAXED, __HIP_MEMORY_SCOPE_AGENT);
    if (slot == 31) {                 // this XCD fully claimed: try to become a winner
      int exp = -1;
      bool ok = __hip_atomic_compare_exchange_strong(winner0, &exp, xcc, __ATOMIC_RELAXED,
                                                     __ATOMIC_RELAXED, __HIP_MEMORY_SCOPE_AGENT);
      if (!ok) {
        exp = -1;
        __hip_atomic_compare_exchange_strong(winner1, &exp, xcc, __ATOMIC_RELAXED,
                                             __ATOMIC_RELAXED, __HIP_MEMORY_SCOPE_AGENT);
      }
    }
    int w0, w1, it = 0;
    do {                              // wait for BOTH winners (R3-proven poll)
      __builtin_amdgcn_s_sleep(8);
      w0 = __hip_atomic_load(winner0, __ATOMIC_RELAXED, __HIP_MEMORY_SCOPE_AGENT);
      w1 = __hip_atomic_load(winner1, __ATOMIC_RELAXED, __HIP_MEMORY_SCOPE_AGENT);
    } while ((w0 < 0 || w1 < 0) && ++it < (1 << 22));
    int role = -1;
    if (slot < 32) {
      if (xcc == w0) role = 0;
      else if (xcc == w1) role = 1;
    }
    s_slot = slot;
    s_role = role;
  }
  __syncthreads();
  const int slot = s_slot, role = s_role;
  if (role < 0) return;

  const int tid = threadIdx.x;
  const int wave = tid >> 6, lane = tid & 63;
  const int lan15 = lane & 15, lanhi = lane >> 4;
  const int c0 = slot * 16;
  const int kw = wave * 128;
  const int ke8 = lanhi * 8;
  const int ob = tid >> 2, oc = (tid & 3) * 4;
  const int ES = GXBF ? 2 : 4;
  const f32x4 z4 = {0.f, 0.f, 0.f, 0.f};

  if (role == 0) {
    // ================= LAYER 0 (producer) — R7-proven loop =================
    const u16* WT0 = WT;
    u16* hb0 = hb;                                   // [2][64][512]
    s16x8 wrz[2][4], whh[4];
#pragma unroll
    for (int g = 0; g < 2; ++g)
#pragma unroll
      for (int ks = 0; ks < 4; ++ks)
        wrz[g][ks] = *(const s16x8*)(WT0 + ((size_t)(g * 512 + c0 + lan15)) * 1024 + 512 + kw + ks * 32 + ke8);
#pragma unroll
    for (int ks = 0; ks < 4; ++ks)
      whh[ks] = *(const s16x8*)(WT0 + ((size_t)(1024 + c0 + lan15)) * 1024 + 512 + kw + ks * 32 + ke8);

    float hown[4];
#pragma unroll
    for (int i = 0; i < 4; ++i) hown[i] = h_in[(ob * 2 + 0) * 512 + c0 + oc + i];

    u32x4 pf_r4 = {0,0,0,0}, pf_z4 = {0,0,0,0}, pf_hc4 = {0,0,0,0}, pf_hn4 = {0,0,0,0};
    u32x2 pf_r2 = {0,0}, pf_z2 = {0,0}, pf_hc2 = {0,0}, pf_hn2 = {0,0};
    auto issue_pf = [&](int tp) {
      const char* gq = (const char*)gx + ((size_t)(tp * 64 + ob) * 1536 + c0 + oc) * ES;
      if constexpr (GXBF) {
        pf_r2 = ld8(gq); pf_z2 = ld8(gq + 1024); pf_hn2 = ld8(gq + 2048);
      } else {
        pf_r4 = ld16(gq); pf_z4 = ld16(gq + 2048); pf_hn4 = ld16(gq + 4096);
      }
    };
    issue_pf(0);

    int cur = 0, tgt = 0;
    for (int t = 0; t < 512; ++t) {
      const u16* hcur = hb0 + cur * (64 * 512);
      u32x4 hl[4][4];
#pragma unroll
      for (int ks = 0; ks < 4; ++ks)
#pragma unroll
        for (int mf = 0; mf < 4; ++mf)
          hl[ks][mf] = ld16(hcur + (mf * 16 + lan15) * 512 + kw + ks * 32 + ke8);
      waitv0();                                  // hl + pf(t) retired
      f32x4 acc[4][2];
#pragma unroll
      for (int i = 0; i < 4; ++i) { acc[i][0] = z4; acc[i][1] = z4; }
#pragma unroll
      for (int ks = 0; ks < 4; ++ks)
#pragma unroll
        for (int mf = 0; mf < 4; ++mf) {
          s16x8 af = __builtin_bit_cast(s16x8, hl[ks][mf]);
          acc[mf][0] = MFMA16(af, wrz[0][ks], acc[mf][0]);
          acc[mf][1] = MFMA16(af, wrz[1][ks], acc[mf][1]);
        }
#pragma unroll
      for (int mf = 0; mf < 4; ++mf)
#pragma unroll
        for (int g = 0; g < 2; ++g)
          *(f32x4*)(red + red_off32(wave, g * 16 + lan15, mf * 16 + lanhi * 4)) = acc[mf][g];
      __syncthreads();
      float zg[4];
      {
        float grf[4], gzf[4];
        unpack4<GXBF>(pf_r4, pf_r2, grf);
        unpack4<GXBF>(pf_z4, pf_z2, gzf);
        u16 rh[4];
#pragma unroll
        for (int i = 0; i < 4; ++i) {
          float rp = grf[i], zp = gzf[i];
#pragma unroll
          for (int w = 0; w < 4; ++w) {
            rp += red[red_off32(w, oc + i, ob)];
            zp += red[red_off32(w, 16 + oc + i, ob)];
          }
          float r = 1.f / (1.f + __expf(-rp));
          zg[i] = 1.f / (1.f + __expf(-zp));
          rh[i] = (u16)f2bf(r * hown[i]);
        }
        st8(rhb0 + ob * 512 + c0 + oc, __builtin_bit_cast(u32x2, rh));
      }
      tgt += 32; gbarA(bar0, tgt);
      // phase 2
      pf_hc4 = pf_hn4; pf_hc2 = pf_hn2;
      u32x4 rl[4][4];
#pragma unroll
      for (int ks = 0; ks < 4; ++ks)
#pragma unroll
        for (int mf = 0; mf < 4; ++mf)
          rl[ks][mf] = ld16(rhb0 + (mf * 16 + lan15) * 512 + kw + ks * 32 + ke8);
      issue_pf(t < 511 ? t + 1 : 511);
      asm volatile("s_waitcnt vmcnt(3)" ::: "memory");
      __builtin_amdgcn_sched_barrier(0);
      f32x4 acc2[4];
#pragma unroll
      for (int i = 0; i < 4; ++i) acc2[i] = z4;
#pragma unroll
      for (int ks = 0; ks < 4; ++ks)
#pragma unroll
        for (int mf = 0; mf < 4; ++mf)
          acc2[mf] = MFMA16(__builtin_bit_cast(s16x8, rl[ks][mf]), whh[ks], acc2[mf]);
#pragma unroll
      for (int mf = 0; mf < 4; ++mf)
        *(f32x4*)(red + red_off32(wave, lan15, mf * 16 + lanhi * 4)) = acc2[mf];
      __syncthreads();
      float hn[4];
      u16 hv[4];
      {
        float ghf[4];
        unpack4<GXBF>(pf_hc4, pf_hc2, ghf);
#pragma unroll
        for (int i = 0; i < 4; ++i) {
          float wp = 0.f;
#pragma unroll
          for (int w = 0; w < 4; ++w) wp += red[red_off32(w, oc + i, ob)];
          float pre = ghf[i] + wp;
          pre = fminf(15.f, fmaxf(-15.f, pre));
          float e = __expf(-2.f * pre);
          float ht = (1.f - e) / (1.f + e);
          hn[i] = (1.f - zg[i]) * hown[i] + zg[i] * ht;
          hown[i] = hn[i];
          hv[i] = (u16)f2bf(hn[i]);
        }
        st8(hb0 + (cur ^ 1) * (64 * 512) + ob * 512 + c0 + oc, __builtin_bit_cast(u32x2, hv));
        // publish ys0(t) cross-XCD BEFORE barrier (drained by gbarA's vmcnt(0))
        st8c(ys0 + ((size_t)ob * 512 + t) * 512 + c0 + oc, __builtin_bit_cast(u32x2, hv));
      }
      cur ^= 1;
      tgt += 32;
      gbarA(bar0, tgt);                          // ALWAYS (t=511 too): gate for prog bump
      if (tid == 0 && slot == 0)                 // all ys0(t) at L3 -> release step t
        __hip_atomic_fetch_add(prog, 1, __ATOMIC_RELAXED, __HIP_MEMORY_SCOPE_AGENT);
      if (t == 511) {
        float* f = finals + (size_t)(ob * 2 + 0) * 512 + c0 + oc;
#pragma unroll
        for (int i = 0; i < 4; ++i) f[i] = hn[i];
      }
    }
  } else {
    // ================= LAYER 1 (consumer) — fused input projection =================
    const u16* WT1 = WT + (size_t)3 * 512 * 1024;
    u16* hb1 = hb + 2 * 64 * 512;                 // layer-1 double buffer
    s16x8 wrz[2][4], whh[4];                      // recurrent (k in [512,1024))
    s16x8 w1rz[2][4], w1h[4];                     // input-proj (k in [0,512))
#pragma unroll
    for (int g = 0; g < 2; ++g)
#pragma unroll
      for (int ks = 0; ks < 4; ++ks) {
        wrz[g][ks]  = *(const s16x8*)(WT1 + ((size_t)(g * 512 + c0 + lan15)) * 1024 + 512 + kw + ks * 32 + ke8);
        w1rz[g][ks] = *(const s16x8*)(WT1 + ((size_t)(g * 512 + c0 + lan15)) * 1024 + kw + ks * 32 + ke8);
      }
#pragma unroll
    for (int ks = 0; ks < 4; ++ks) {
      whh[ks] = *(const s16x8*)(WT1 + ((size_t)(1024 + c0 + lan15)) * 1024 + 512 + kw + ks * 32 + ke8);
      w1h[ks] = *(const s16x8*)(WT1 + ((size_t)(1024 + c0 + lan15)) * 1024 + kw + ks * 32 + ke8);
    }
    float brv[4], bzv[4], bhv[4];
#pragma unroll
    for (int i = 0; i < 4; ++i) {
      brv[i] = br[512 + c0 + oc + i];
      bzv[i] = bz[512 + c0 + oc + i];
      bhv[i] = bh[512 + c0 + oc + i];
    }
    float hown[4];
#pragma unroll
    for (int i = 0; i < 4; ++i) hown[i] = h_in[(ob * 2 + 1) * 512 + c0 + oc + i];

    int cur = 0, tgt = 0;
    for (int t = 0; t < 512; ++t) {
      // ---- wait for producer step t ----
      if (tid == 0) {
        int pv, it = 0;
        do {
          pv = __hip_atomic_load(prog, __ATOMIC_RELAXED, __HIP_MEMORY_SCOPE_AGENT);
          if (pv > t) break;
          __builtin_amdgcn_s_sleep(2);
        } while (++it < (1 << 16));              // watchdog
      }
      __syncthreads();
      __builtin_amdgcn_sched_barrier(0);
      const u16* hcur = hb1 + cur * (64 * 512);
      // phase 1: issue ys0(t) (L3) first, then h1 (local L2); one wait
      u32x4 yl[4][4], hl[4][4];
#pragma unroll
      for (int ks = 0; ks < 4; ++ks)
#pragma unroll
        for (int mf = 0; mf < 4; ++mf)
          yl[ks][mf] = ld16c(ys0 + ((size_t)(mf * 16 + lan15) * 512 + t) * 512 + kw + ks * 32 + ke8);
#pragma unroll
      for (int ks = 0; ks < 4; ++ks)
#pragma unroll
        for (int mf = 0; mf < 4; ++mf)
          hl[ks][mf] = ld16(hcur + (mf * 16 + lan15) * 512 + kw + ks * 32 + ke8);
      waitv0();
      f32x4 acc[4][2];
#pragma unroll
      for (int i = 0; i < 4; ++i) { acc[i][0] = z4; acc[i][1] = z4; }
#pragma unroll
      for (int ks = 0; ks < 4; ++ks)
#pragma unroll
        for (int mf = 0; mf < 4; ++mf) {
          s16x8 ah = __builtin_bit_cast(s16x8, hl[ks][mf]);
          s16x8 ay = __builtin_bit_cast(s16x8, yl[ks][mf]);
          acc[mf][0] = MFMA16(ah, wrz[0][ks], acc[mf][0]);
          acc[mf][0] = MFMA16(ay, w1rz[0][ks], acc[mf][0]);
          acc[mf][1] = MFMA16(ah, wrz[1][ks], acc[mf][1]);
          acc[mf][1] = MFMA16(ay, w1rz[1][ks], acc[mf][1]);
        }
#pragma unroll
      for (int mf = 0; mf < 4; ++mf)
#pragma unroll
        for (int g = 0; g < 2; ++g)
          *(f32x4*)(red + red_off32(wave, g * 16 + lan15, mf * 16 + lanhi * 4)) = acc[mf][g];
      __syncthreads();
      float zg[4];
      {
        u16 rh[4];
#pragma unroll
        for (int i = 0; i < 4; ++i) {
          float rp = brv[i], zp = bzv[i];
#pragma unroll
          for (int w = 0; w < 4; ++w) {
            rp += red[red_off32(w, oc + i, ob)];
            zp += red[red_off32(w, 16 + oc + i, ob)];
          }
          float r = 1.f / (1.f + __expf(-rp));
          zg[i] = 1.f / (1.f + __expf(-zp));
          rh[i] = (u16)f2bf(r * hown[i]);
        }
        st8(rhb1 + ob * 512 + c0 + oc, __builtin_bit_cast(u32x2, rh));
      }
      tgt += 32; gbarA(bar1, tgt);
      // phase 2
      u32x4 rl[4][4], yl2[4][4];
#pragma unroll
      for (int ks = 0; ks < 4; ++ks)
#pragma unroll
        for (int mf = 0; mf < 4; ++mf)
          yl2[ks][mf] = ld16c(ys0 + ((size_t)(mf * 16 + lan15) * 512 + t) * 512 + kw + ks * 32 + ke8);
#pragma unroll
      for (int ks = 0; ks < 4; ++ks)
#pragma unroll
        for (int mf = 0; mf < 4; ++mf)
          rl[ks][mf] = ld16(rhb1 + (mf * 16 + lan15) * 512 + kw + ks * 32 + ke8);
      waitv0();
      f32x4 acc2[4];
#pragma unroll
      for (int i = 0; i < 4; ++i) acc2[i] = z4;
#pragma unroll
      for (int ks = 0; ks < 4; ++ks)
#pragma unroll
        for (int mf = 0; mf < 4; ++mf) {
          acc2[mf] = MFMA16(__builtin_bit_cast(s16x8, rl[ks][mf]), whh[ks], acc2[mf]);
          acc2[mf] = MFMA16(__builtin_bit_cast(s16x8, yl2[ks][mf]), w1h[ks], acc2[mf]);
        }
#pragma unroll
      for (int mf = 0; mf < 4; ++mf)
        *(f32x4*)(red + red_off32(wave, lan15, mf * 16 + lanhi * 4)) = acc2[mf];
      __syncthreads();
      float hn[4];
      {
#pragma unroll
        for (int i = 0; i < 4; ++i) {
          float wp = bhv[i];
#pragma unroll
          for (int w = 0; w < 4; ++w) wp += red[red_off32(w, oc + i, ob)];
          float pre = fminf(15.f, fmaxf(-15.f, wp));
          float e = __expf(-2.f * pre);
          float ht = (1.f - e) / (1.f + e);
          hn[i] = (1.f - zg[i]) * hown[i] + zg[i] * ht;
          hown[i] = hn[i];
        }
        u16 hv[4];
#pragma unroll
        for (int i = 0; i < 4; ++i) hv[i] = (u16)f2bf(hn[i]);
        st8(hb1 + (cur ^ 1) * (64 * 512) + ob * 512 + c0 + oc, __builtin_bit_cast(u32x2, hv));
      }
      cur ^= 1;
      tgt += 32;
      if (t != 511) gbarA(bar1, tgt);
      // outputs post-barrier
      f32x4 o = {hn[0], hn[1], hn[2], hn[3]};
      st16(out_f32 + ((size_t)ob * 512 + t) * 512 + c0 + oc, __builtin_bit_cast(u32x4, o));
      if (t == 511) {
        float* f = finals + (size_t)(ob * 2 + 1) * 512 + c0 + oc;
#pragma unroll
        for (int i = 0; i < 4; ++i) f[i] = hn[i];
      }
    }
  }
}

template <int GXBF>
static void run_all(const float* x, const float* h, const float* Wr, const float* br,
                    const float* Wz, const float* bz, const float* Wh, const float* bh,
                    float* out, char* ws, hipStream_t stream) {
  int* sync  = (int*)(ws + OFF_SYNC);
  u16* hbAll = (u16*)(ws + OFF_HB);
  u16* rhb0  = (u16*)(ws + OFF_RHB0);
  u16* rhb1  = (u16*)(ws + OFF_RHB1);
  u16* WT    = (u16*)(ws + OFF_WT);
  u16* ys0   = (u16*)(ws + OFF_YS0);
  void* gx   = (void*)(ws + OFF_GX);
  float* finals = out + 16777216;

  init_kernel<<<64, 256, 0, stream>>>(h, hbAll, sync);
  convert_w_kernel<<<12288, 256, 0, stream>>>(Wr, Wz, Wh, WT);
  proj_kernel<GXBF><<<3072, 256, 0, stream>>>(x, WT, br, bz, bh, gx);
  gru_pipe<GXBF><<<256, 256, 0, stream>>>(gx, WT, h, hbAll, rhb0, rhb1, ys0,
                                          br, bz, bh, out, finals, sync);
}

extern "C" void kernel_launch(void* const* d_in, const int* in_sizes, int n_in,
                              void* d_out, int out_size, void* d_ws, size_t ws_size,
                              hipStream_t stream) {
  const float* x  = (const float*)d_in[0];
  const float* h  = (const float*)d_in[1];
  const float* Wr = (const float*)d_in[2];
  const float* br = (const float*)d_in[3];
  const float* Wz = (const float*)d_in[4];
  const float* bz = (const float*)d_in[5];
  const float* Wh = (const float*)d_in[6];
  const float* bh = (const float*)d_in[7];
  float* out = (float*)d_out;
  char* ws = (char*)d_ws;

  const size_t need_f32 = OFF_GX + GX_ELEMS * 4;   // 241,546,752 B (230.4 MiB)
  const size_t need_bf  = OFF_GX + GX_ELEMS * 2;   // 140,883,456 B (134.3 MiB)

  if (ws_size >= need_f32) {
    run_all<0>(x, h, Wr, br, Wz, bz, Wh, bh, out, ws, stream);
  } else if (ws_size >= need_bf) {
    run_all<1>(x, h, Wr, br, Wz, bz, Wh, bh, out, ws, stream);
  } else {
    sentinel_kernel<<<1, 64, 0, stream>>>(out, (float)ws_size);
  }
}

// Round 11
// 5228.211 us; speedup vs baseline: 1.5719x; 1.1904x over previous
//
#include <hip/hip_runtime.h>

typedef unsigned int uint;
typedef unsigned short u16;
typedef short s16x8 __attribute__((ext_vector_type(8)));
typedef float f32x4 __attribute__((ext_vector_type(4)));
typedef uint u32x4 __attribute__((ext_vector_type(4)));
typedef uint u32x2 __attribute__((ext_vector_type(2)));

#define MFMA16(a, b, c) __builtin_amdgcn_mfma_f32_16x16x32_bf16((a), (b), (c), 0, 0, 0)

// ---- problem constants ----
// B=64, S=512, D=512, H=512, L=2
// sync region (256 ints = 1024 B):
//   [0] bar0 (own 128B line)  [32] bar1 (own 128B line)
//   [64..71] claim (per-XCD)  [80] winner0  [81] winner1  (L3-scope agent atomics)
//   [96] prog0 (own 128B line, L3-scope agent atomics)
static const size_t OFF_SYNC = 0;                      // 1024 B
static const size_t OFF_HB   = 1024;                   // [2 layers][2 bufs][64][512] bf16 = 262144
static const size_t OFF_RHB0 = 263168;                 // [64][512] bf16 = 65536
static const size_t OFF_RHB1 = 328704;                 // [64][512] bf16 = 65536
static const size_t OFF_WT   = 394240;                 // [2][3][512][1024] bf16 = 6291456
static const size_t OFF_YS0  = 6685696;                // [64][512][512] bf16 = 33554432
static const size_t OFF_GX   = 40240128;               // [512][64][1536] f32 or bf16 (layer 0 only)
static const size_t GX_ELEMS = (size_t)512 * 64 * 1536;

__device__ __forceinline__ short f2bf(float x) {       // RNE float->bf16
  uint u = __builtin_bit_cast(uint, x);
  u = u + 0x7fffu + ((u >> 16) & 1u);
  return (short)(u >> 16);
}
__device__ __forceinline__ float bf2f(u16 v) {
  uint u = ((uint)v) << 16;
  return __builtin_bit_cast(float, u);
}

// ---- raw memory ops ----
__device__ __forceinline__ u32x4 ld16(const void* p) {          // plain: L1 + local L2
  u32x4 r;
  asm volatile("global_load_dwordx4 %0, %1, off" : "=v"(r) : "v"(p));
  return r;
}
__device__ __forceinline__ u32x2 ld8(const void* p) {
  u32x2 r;
  asm volatile("global_load_dwordx2 %0, %1, off" : "=v"(r) : "v"(p));
  return r;
}
__device__ __forceinline__ void st16(void* p, u32x4 v) {
  asm volatile("global_store_dwordx4 %0, %1, off" :: "v"(p), "v"(v));
}
__device__ __forceinline__ void st8(void* p, u32x2 v) {
  asm volatile("global_store_dwordx2 %0, %1, off" :: "v"(p), "v"(v));
}
// cross-XCD coherent (system scope, served at L3): sc0 sc1 — R3-proven combo
__device__ __forceinline__ u32x4 ld16c(const void* p) {
  u32x4 r;
  asm volatile("global_load_dwordx4 %0, %1, off sc0 sc1" : "=v"(r) : "v"(p));
  return r;
}
__device__ __forceinline__ void st8c(void* p, u32x2 v) {
  asm volatile("global_store_dwordx2 %0, %1, off sc0 sc1" :: "v"(p), "v"(v));
}
__device__ __forceinline__ void waitv0() {
  asm volatile("s_waitcnt vmcnt(0)" ::: "memory");
  __builtin_amdgcn_sched_barrier(0);   // rule #18
}

// ---------------- sentinel ----------------
__global__ void sentinel_kernel(float* __restrict__ out, float v) {
  out[threadIdx.x] = v;
}

// ---------------- init: sync words, h0 -> bf16 ----------------
__global__ void init_kernel(const float* __restrict__ h_in, u16* __restrict__ hb,
                            int* __restrict__ sync) {
  int idx = blockIdx.x * 256 + threadIdx.x;
  if (idx < 256) sync[idx] = (idx == 80 || idx == 81) ? -1 : 0;   // winners = -1
  for (int i = idx; i < 2 * 64 * 512; i += gridDim.x * 256) {
    int l = i >> 15, b = (i >> 9) & 63, c = i & 511;
    hb[l * 65536 + b * 512 + c] = (u16)f2bf(h_in[(b * 2 + l) * 512 + c]);
  }
}

// ---------------- W (L,1024,512) f32 -> WT[l][g][n][k] bf16 (k-major) ----------------
__global__ void convert_w_kernel(const float* __restrict__ Wr, const float* __restrict__ Wz,
                                 const float* __restrict__ Wh, u16* __restrict__ WT) {
  int idx = blockIdx.x * 256 + threadIdx.x;       // 6*512*1024 = 3145728 total
  int n = idx & 511, k = (idx >> 9) & 1023, lg = idx >> 19;
  int l = (lg >= 3) ? 1 : 0, g = lg - l * 3;
  const float* W = (g == 0 ? Wr : (g == 1 ? Wz : Wh)) + (size_t)l * 1024 * 512;
  WT[((size_t)lg * 512 + n) * 1024 + k] = (u16)f2bf(W[k * 512 + n]);
}

// ---------------- input projection GEMM (layer 0 only) ----------------
template <int GXBF>
__global__ __launch_bounds__(256) void proj_kernel(
    const float* __restrict__ A, const u16* __restrict__ WT,
    const float* __restrict__ br, const float* __restrict__ bz, const float* __restrict__ bh,
    void* __restrict__ gx) {
  __shared__ u16 Alds[128 * 64];
  __shared__ u16 Blds[128 * 64];
  const int tid = threadIdx.x;
  const int wave = tid >> 6, lane = tid & 63;
  const int lan15 = lane & 15, lanhi = lane >> 4;
  const int mb = blockIdx.x & 255, nb = blockIdx.x >> 8;
  const int m0 = mb * 128, n0 = nb * 128;
  const int wm = (wave >> 1) * 64, wn = (wave & 1) * 64;

  const f32x4 z4 = {0.f, 0.f, 0.f, 0.f};
  f32x4 acc[4][4];
#pragma unroll
  for (int i = 0; i < 4; ++i)
#pragma unroll
    for (int j = 0; j < 4; ++j) acc[i][j] = z4;

  for (int kb = 0; kb < 512; kb += 64) {
    __syncthreads();
#pragma unroll
    for (int p = 0; p < 4; ++p) {        // stage+convert A tile 128x64 (XOR-swizzled 16B slots)
      int idx = p * 256 + tid;
      int row = idx >> 3, slot = idx & 7;
      const float* src = A + (size_t)(m0 + row) * 512 + kb + slot * 8;
      float4 v0 = *(const float4*)src;
      float4 v1 = *(const float4*)(src + 4);
      u16 tmp[8] = {(u16)f2bf(v0.x), (u16)f2bf(v0.y), (u16)f2bf(v0.z), (u16)f2bf(v0.w),
                    (u16)f2bf(v1.x), (u16)f2bf(v1.y), (u16)f2bf(v1.z), (u16)f2bf(v1.w)};
      *(uint4*)((char*)Alds + row * 128 + ((slot ^ (row & 7)) * 16)) = *(uint4*)tmp;
    }
#pragma unroll
    for (int p = 0; p < 4; ++p) {        // stage B tile 128x64 from WT (n-major rows)
      int idx = p * 256 + tid;
      int row = idx >> 3, slot = idx & 7;
      int ng = n0 + row, g = ng >> 9, nc = ng & 511;
      uint4 v = *(const uint4*)(WT + ((size_t)g * 512 + nc) * 1024 + kb + slot * 8);
      *(uint4*)((char*)Blds + row * 128 + ((slot ^ (row & 7)) * 16)) = v;
    }
    __syncthreads();
#pragma unroll
    for (int ks = 0; ks < 2; ++ks) {
      s16x8 af[4], bfr[4];
#pragma unroll
      for (int f = 0; f < 4; ++f) {
        int rowA = wm + f * 16 + lan15;
        af[f] = *(const s16x8*)((const char*)Alds + rowA * 128 + (((ks * 4 + lanhi) ^ (rowA & 7)) * 16));
        int rowB = wn + f * 16 + lan15;
        bfr[f] = *(const s16x8*)((const char*)Blds + rowB * 128 + (((ks * 4 + lanhi) ^ (rowB & 7)) * 16));
      }
#pragma unroll
      for (int mf = 0; mf < 4; ++mf)
#pragma unroll
        for (int nf = 0; nf < 4; ++nf)
          acc[mf][nf] = MFMA16(af[mf], bfr[nf], acc[mf][nf]);
    }
  }
#pragma unroll
  for (int nf = 0; nf < 4; ++nf) {
    int n = n0 + wn + nf * 16 + lan15;
    int g = n >> 9, nc = n & 511;
    float bias = (g == 0 ? br[nc] : (g == 1 ? bz[nc] : bh[nc]));
#pragma unroll
    for (int mf = 0; mf < 4; ++mf) {
#pragma unroll
      for (int q = 0; q < 4; ++q) {
        int m = m0 + wm + mf * 16 + lanhi * 4 + q;
        int s = m & 511, b = m >> 9;
        size_t e = (size_t)(s * 64 + b) * 1536 + n;
        float v = acc[mf][nf][q] + bias;
        if constexpr (GXBF) ((u16*)gx)[e] = (u16)f2bf(v);
        else ((float*)gx)[e] = v;
      }
    }
  }
}

// ---------------- XCD-local barrier: L2-executed atomics (R6/R7-proven) ----------------
__device__ __forceinline__ void gbarA(int* bar, int target) {
  asm volatile("s_waitcnt vmcnt(0)" ::: "memory");
  __syncthreads();
  if (threadIdx.x == 0) {
    int one = 1;
    asm volatile("global_atomic_add %0, %1, off" :: "v"(bar), "v"(one) : "memory");
    int v, zero = 0, iter = 0;
    do {
      __builtin_amdgcn_s_sleep(1);
      asm volatile("global_atomic_add %0, %1, %2, off sc0\n\ts_waitcnt vmcnt(0)"
                   : "=v"(v) : "v"(bar), "v"(zero) : "memory");
    } while (v < target && ++iter < (1 << 17));      // watchdog
  }
  __syncthreads();
  __builtin_amdgcn_sched_barrier(0);
}

// red buffer: [4 waves][32 cols][64 batches] f32, 16B-slot XOR swizzle on batch
__device__ __forceinline__ int red_off32(int w, int c, int b) {
  return ((w * 32 + c) << 6) + ((((b >> 2) ^ (c & 15)) & 15) << 2) + (b & 3);
}

template <int GXBF>
__device__ __forceinline__ void unpack4(const u32x4& a4, const u32x2& a2, float o[4]) {
  if constexpr (GXBF) {
    const u16* p = (const u16*)&a2;
#pragma unroll
    for (int i = 0; i < 4; ++i) o[i] = bf2f(p[i]);
  } else {
    const float* p = (const float*)&a4;
#pragma unroll
    for (int i = 0; i < 4; ++i) o[i] = p[i];
  }
}

// ---------------- persistent pipelined GRU: both layers concurrently ----------------
// grid=256, 84KB LDS -> 1 WG/CU -> each XCD hosts exactly 32 WGs.
// winner0 XCD runs layer 0 (producer); winner1 XCD runs layer 1 (consumer) with fused
// input projection; ys0(t) handed off via L3 (sc0 sc1) gated by the prog counter.
// Consumer (vs R9): ys0 loaded ONCE per step into yl (reused in phase 2), and the next
// step's yl is prefetched into the SAME registers after the last barrier of the step
// (register-neutral; drains at t+1's phase-1 waitv0).
template <int GXBF>
__global__ __launch_bounds__(256, 1) void gru_pipe(
    const void* __restrict__ gx,     // [512][64][1536] layer-0 gates
    const u16* __restrict__ WT,      // [2][3][512][1024]
    const float* __restrict__ h_in,  // [64][2][512]
    u16* __restrict__ hb,            // [2 layers][2 bufs][64][512]
    u16* __restrict__ rhb0, u16* __restrict__ rhb1,
    u16* __restrict__ ys0,           // [64][512][512] bf16 (L0 -> L1 handoff via L3)
    const float* __restrict__ br, const float* __restrict__ bz, const float* __restrict__ bh,
    float* __restrict__ out_f32,     // d_out [64][512][512] f32
    float* __restrict__ finals,      // d_out + B*S*H  [64][2][512]
    int* __restrict__ sync) {
  __shared__ float red[21504];       // 84 KiB: forces 1 WG/CU
  __shared__ int s_slot, s_role;

  int* bar0 = sync + 0;
  int* bar1 = sync + 32;
  int* claim = sync + 64;
  int* winner0 = sync + 80;
  int* winner1 = sync + 81;
  int* prog = sync + 96;

  // ---- election: two winner XCDs ----
  if (threadIdx.x == 0) {
    int xcc;
    asm volatile("s_getreg_b32 %0, hwreg(HW_REG_XCC_ID)" : "=s"(xcc));
    xcc &= 7;
    int slot = __hip_atomic_fetch_add(&claim[xcc], 1, __ATOMIC_RELAXED, __HIP_MEMORY_SCOPE_AGENT);
    if (slot == 31) {                 // this XCD fully claimed: try to become a winner
      int exp = -1;
      bool ok = __hip_atomic_compare_exchange_strong(winner0, &exp, xcc, __ATOMIC_RELAXED,
                                                     __ATOMIC_RELAXED, __HIP_MEMORY_SCOPE_AGENT);
      if (!ok) {
        exp = -1;
        __hip_atomic_compare_exchange_strong(winner1, &exp, xcc, __ATOMIC_RELAXED,
                                             __ATOMIC_RELAXED, __HIP_MEMORY_SCOPE_AGENT);
      }
    }
    int w0, w1, it = 0;
    do {                              // wait for BOTH winners (R3-proven poll)
      __builtin_amdgcn_s_sleep(8);
      w0 = __hip_atomic_load(winner0, __ATOMIC_RELAXED, __HIP_MEMORY_SCOPE_AGENT);
      w1 = __hip_atomic_load(winner1, __ATOMIC_RELAXED, __HIP_MEMORY_SCOPE_AGENT);
    } while ((w0 < 0 || w1 < 0) && ++it < (1 << 22));
    int role = -1;
    if (slot < 32) {
      if (xcc == w0) role = 0;
      else if (xcc == w1) role = 1;
    }
    s_slot = slot;
    s_role = role;
  }
  __syncthreads();
  const int slot = s_slot, role = s_role;
  if (role < 0) return;

  const int tid = threadIdx.x;
  const int wave = tid >> 6, lane = tid & 63;
  const int lan15 = lane & 15, lanhi = lane >> 4;
  const int c0 = slot * 16;
  const int kw = wave * 128;
  const int ke8 = lanhi * 8;
  const int ob = tid >> 2, oc = (tid & 3) * 4;
  const int ES = GXBF ? 2 : 4;
  const f32x4 z4 = {0.f, 0.f, 0.f, 0.f};

  if (role == 0) {
    // ================= LAYER 0 (producer) — R7/R9-proven loop =================
    const u16* WT0 = WT;
    u16* hb0 = hb;                                   // [2][64][512]
    s16x8 wrz[2][4], whh[4];
#pragma unroll
    for (int g = 0; g < 2; ++g)
#pragma unroll
      for (int ks = 0; ks < 4; ++ks)
        wrz[g][ks] = *(const s16x8*)(WT0 + ((size_t)(g * 512 + c0 + lan15)) * 1024 + 512 + kw + ks * 32 + ke8);
#pragma unroll
    for (int ks = 0; ks < 4; ++ks)
      whh[ks] = *(const s16x8*)(WT0 + ((size_t)(1024 + c0 + lan15)) * 1024 + 512 + kw + ks * 32 + ke8);

    float hown[4];
#pragma unroll
    for (int i = 0; i < 4; ++i) hown[i] = h_in[(ob * 2 + 0) * 512 + c0 + oc + i];

    u32x4 pf_r4 = {0,0,0,0}, pf_z4 = {0,0,0,0}, pf_hc4 = {0,0,0,0}, pf_hn4 = {0,0,0,0};
    u32x2 pf_r2 = {0,0}, pf_z2 = {0,0}, pf_hc2 = {0,0}, pf_hn2 = {0,0};
    auto issue_pf = [&](int tp) {
      const char* gq = (const char*)gx + ((size_t)(tp * 64 + ob) * 1536 + c0 + oc) * ES;
      if constexpr (GXBF) {
        pf_r2 = ld8(gq); pf_z2 = ld8(gq + 1024); pf_hn2 = ld8(gq + 2048);
      } else {
        pf_r4 = ld16(gq); pf_z4 = ld16(gq + 2048); pf_hn4 = ld16(gq + 4096);
      }
    };
    issue_pf(0);

    int cur = 0, tgt = 0;
    for (int t = 0; t < 512; ++t) {
      const u16* hcur = hb0 + cur * (64 * 512);
      u32x4 hl[4][4];
#pragma unroll
      for (int ks = 0; ks < 4; ++ks)
#pragma unroll
        for (int mf = 0; mf < 4; ++mf)
          hl[ks][mf] = ld16(hcur + (mf * 16 + lan15) * 512 + kw + ks * 32 + ke8);
      waitv0();                                  // hl + pf(t) retired
      f32x4 acc[4][2];
#pragma unroll
      for (int i = 0; i < 4; ++i) { acc[i][0] = z4; acc[i][1] = z4; }
#pragma unroll
      for (int ks = 0; ks < 4; ++ks)
#pragma unroll
        for (int mf = 0; mf < 4; ++mf) {
          s16x8 af = __builtin_bit_cast(s16x8, hl[ks][mf]);
          acc[mf][0] = MFMA16(af, wrz[0][ks], acc[mf][0]);
          acc[mf][1] = MFMA16(af, wrz[1][ks], acc[mf][1]);
        }
#pragma unroll
      for (int mf = 0; mf < 4; ++mf)
#pragma unroll
        for (int g = 0; g < 2; ++g)
          *(f32x4*)(red + red_off32(wave, g * 16 + lan15, mf * 16 + lanhi * 4)) = acc[mf][g];
      __syncthreads();
      float zg[4];
      {
        float grf[4], gzf[4];
        unpack4<GXBF>(pf_r4, pf_r2, grf);
        unpack4<GXBF>(pf_z4, pf_z2, gzf);
        u16 rh[4];
#pragma unroll
        for (int i = 0; i < 4; ++i) {
          float rp = grf[i], zp = gzf[i];
#pragma unroll
          for (int w = 0; w < 4; ++w) {
            rp += red[red_off32(w, oc + i, ob)];
            zp += red[red_off32(w, 16 + oc + i, ob)];
          }
          float r = 1.f / (1.f + __expf(-rp));
          zg[i] = 1.f / (1.f + __expf(-zp));
          rh[i] = (u16)f2bf(r * hown[i]);
        }
        st8(rhb0 + ob * 512 + c0 + oc, __builtin_bit_cast(u32x2, rh));
      }
      tgt += 32; gbarA(bar0, tgt);
      // phase 2
      pf_hc4 = pf_hn4; pf_hc2 = pf_hn2;
      u32x4 rl[4][4];
#pragma unroll
      for (int ks = 0; ks < 4; ++ks)
#pragma unroll
        for (int mf = 0; mf < 4; ++mf)
          rl[ks][mf] = ld16(rhb0 + (mf * 16 + lan15) * 512 + kw + ks * 32 + ke8);
      issue_pf(t < 511 ? t + 1 : 511);
      asm volatile("s_waitcnt vmcnt(3)" ::: "memory");
      __builtin_amdgcn_sched_barrier(0);
      f32x4 acc2[4];
#pragma unroll
      for (int i = 0; i < 4; ++i) acc2[i] = z4;
#pragma unroll
      for (int ks = 0; ks < 4; ++ks)
#pragma unroll
        for (int mf = 0; mf < 4; ++mf)
          acc2[mf] = MFMA16(__builtin_bit_cast(s16x8, rl[ks][mf]), whh[ks], acc2[mf]);
#pragma unroll
      for (int mf = 0; mf < 4; ++mf)
        *(f32x4*)(red + red_off32(wave, lan15, mf * 16 + lanhi * 4)) = acc2[mf];
      __syncthreads();
      float hn[4];
      u16 hv[4];
      {
        float ghf[4];
        unpack4<GXBF>(pf_hc4, pf_hc2, ghf);
#pragma unroll
        for (int i = 0; i < 4; ++i) {
          float wp = 0.f;
#pragma unroll
          for (int w = 0; w < 4; ++w) wp += red[red_off32(w, oc + i, ob)];
          float pre = ghf[i] + wp;
          pre = fminf(15.f, fmaxf(-15.f, pre));
          float e = __expf(-2.f * pre);
          float ht = (1.f - e) / (1.f + e);
          hn[i] = (1.f - zg[i]) * hown[i] + zg[i] * ht;
          hown[i] = hn[i];
          hv[i] = (u16)f2bf(hn[i]);
        }
        st8(hb0 + (cur ^ 1) * (64 * 512) + ob * 512 + c0 + oc, __builtin_bit_cast(u32x2, hv));
        // publish ys0(t) cross-XCD BEFORE barrier (drained by gbarA's vmcnt(0))
        st8c(ys0 + ((size_t)ob * 512 + t) * 512 + c0 + oc, __builtin_bit_cast(u32x2, hv));
      }
      cur ^= 1;
      tgt += 32;
      gbarA(bar0, tgt);                          // ALWAYS (t=511 too): gate for prog bump
      if (tid == 0 && slot == 0)                 // all ys0(t) at L3 -> release step t
        __hip_atomic_fetch_add(prog, 1, __ATOMIC_RELAXED, __HIP_MEMORY_SCOPE_AGENT);
      if (t == 511) {
        float* f = finals + (size_t)(ob * 2 + 0) * 512 + c0 + oc;
#pragma unroll
        for (int i = 0; i < 4; ++i) f[i] = hn[i];
      }
    }
  } else {
    // ============ LAYER 1 (consumer) — fused input proj, single-buffer yl prefetch ============
    const u16* WT1 = WT + (size_t)3 * 512 * 1024;
    u16* hb1 = hb + 2 * 64 * 512;                 // layer-1 double buffer
    s16x8 wrz[2][4], whh[4];                      // recurrent (k in [512,1024))
    s16x8 w1rz[2][4], w1h[4];                     // input-proj (k in [0,512))
#pragma unroll
    for (int g = 0; g < 2; ++g)
#pragma unroll
      for (int ks = 0; ks < 4; ++ks) {
        wrz[g][ks]  = *(const s16x8*)(WT1 + ((size_t)(g * 512 + c0 + lan15)) * 1024 + 512 + kw + ks * 32 + ke8);
        w1rz[g][ks] = *(const s16x8*)(WT1 + ((size_t)(g * 512 + c0 + lan15)) * 1024 + kw + ks * 32 + ke8);
      }
#pragma unroll
    for (int ks = 0; ks < 4; ++ks) {
      whh[ks] = *(const s16x8*)(WT1 + ((size_t)(1024 + c0 + lan15)) * 1024 + 512 + kw + ks * 32 + ke8);
      w1h[ks] = *(const s16x8*)(WT1 + ((size_t)(1024 + c0 + lan15)) * 1024 + kw + ks * 32 + ke8);
    }
    float brv[4], bzv[4], bhv[4];
#pragma unroll
    for (int i = 0; i < 4; ++i) {
      brv[i] = br[512 + c0 + oc + i];
      bzv[i] = bz[512 + c0 + oc + i];
      bhv[i] = bh[512 + c0 + oc + i];
    }
    float hown[4];
#pragma unroll
    for (int i = 0; i < 4; ++i) hown[i] = h_in[(ob * 2 + 1) * 512 + c0 + oc + i];

    u32x4 yl[4][4];                               // ys0 fragments (single buffer)

    // prologue: wait for producer step 0, issue yl(0) — drains at step 0's waitv0
    if (tid == 0) {
      int pv, it = 0;
      do {
        pv = __hip_atomic_load(prog, __ATOMIC_RELAXED, __HIP_MEMORY_SCOPE_AGENT);
        if (pv > 0) break;
        __builtin_amdgcn_s_sleep(2);
      } while (++it < (1 << 20));
    }
    __syncthreads();
    __builtin_amdgcn_sched_barrier(0);
#pragma unroll
    for (int ks = 0; ks < 4; ++ks)
#pragma unroll
      for (int mf = 0; mf < 4; ++mf)
        yl[ks][mf] = ld16c(ys0 + ((size_t)(mf * 16 + lan15) * 512 + 0) * 512 + kw + ks * 32 + ke8);

    int cur = 0, tgt = 0;
    for (int t = 0; t < 512; ++t) {
      const u16* hcur = hb1 + cur * (64 * 512);
      u32x4 hl[4][4];
#pragma unroll
      for (int ks = 0; ks < 4; ++ks)
#pragma unroll
        for (int mf = 0; mf < 4; ++mf)
          hl[ks][mf] = ld16(hcur + (mf * 16 + lan15) * 512 + kw + ks * 32 + ke8);
      waitv0();                                  // hl + prefetched yl retired
      f32x4 acc[4][2];
#pragma unroll
      for (int i = 0; i < 4; ++i) { acc[i][0] = z4; acc[i][1] = z4; }
#pragma unroll
      for (int ks = 0; ks < 4; ++ks)
#pragma unroll
        for (int mf = 0; mf < 4; ++mf) {
          s16x8 ah = __builtin_bit_cast(s16x8, hl[ks][mf]);
          s16x8 ay = __builtin_bit_cast(s16x8, yl[ks][mf]);
          acc[mf][0] = MFMA16(ah, wrz[0][ks], acc[mf][0]);
          acc[mf][0] = MFMA16(ay, w1rz[0][ks], acc[mf][0]);
          acc[mf][1] = MFMA16(ah, wrz[1][ks], acc[mf][1]);
          acc[mf][1] = MFMA16(ay, w1rz[1][ks], acc[mf][1]);
        }
#pragma unroll
      for (int mf = 0; mf < 4; ++mf)
#pragma unroll
        for (int g = 0; g < 2; ++g)
          *(f32x4*)(red + red_off32(wave, g * 16 + lan15, mf * 16 + lanhi * 4)) = acc[mf][g];
      __syncthreads();
      float zg[4];
      {
        u16 rh[4];
#pragma unroll
        for (int i = 0; i < 4; ++i) {
          float rp = brv[i], zp = bzv[i];
#pragma unroll
          for (int w = 0; w < 4; ++w) {
            rp += red[red_off32(w, oc + i, ob)];
            zp += red[red_off32(w, 16 + oc + i, ob)];
          }
          float r = 1.f / (1.f + __expf(-rp));
          zg[i] = 1.f / (1.f + __expf(-zp));
          rh[i] = (u16)f2bf(r * hown[i]);
        }
        st8(rhb1 + ob * 512 + c0 + oc, __builtin_bit_cast(u32x2, rh));
      }
      tgt += 32; gbarA(bar1, tgt);
      // phase 2: rl loads only; ys0 reused from yl registers
      u32x4 rl[4][4];
#pragma unroll
      for (int ks = 0; ks < 4; ++ks)
#pragma unroll
        for (int mf = 0; mf < 4; ++mf)
          rl[ks][mf] = ld16(rhb1 + (mf * 16 + lan15) * 512 + kw + ks * 32 + ke8);
      waitv0();
      f32x4 acc2[4];
#pragma unroll
      for (int i = 0; i < 4; ++i) acc2[i] = z4;
#pragma unroll
      for (int ks = 0; ks < 4; ++ks)
#pragma unroll
        for (int mf = 0; mf < 4; ++mf) {
          acc2[mf] = MFMA16(__builtin_bit_cast(s16x8, rl[ks][mf]), whh[ks], acc2[mf]);
          acc2[mf] = MFMA16(__builtin_bit_cast(s16x8, yl[ks][mf]), w1h[ks], acc2[mf]);
        }
#pragma unroll
      for (int mf = 0; mf < 4; ++mf)
        *(f32x4*)(red + red_off32(wave, lan15, mf * 16 + lanhi * 4)) = acc2[mf];
      __syncthreads();
      float hn[4];
      {
#pragma unroll
        for (int i = 0; i < 4; ++i) {
          float wp = bhv[i];
#pragma unroll
          for (int w = 0; w < 4; ++w) wp += red[red_off32(w, oc + i, ob)];
          float pre = fminf(15.f, fmaxf(-15.f, wp));
          float e = __expf(-2.f * pre);
          float ht = (1.f - e) / (1.f + e);
          hn[i] = (1.f - zg[i]) * hown[i] + zg[i] * ht;
          hown[i] = hn[i];
        }
        u16 hv[4];
#pragma unroll
        for (int i = 0; i < 4; ++i) hv[i] = (u16)f2bf(hn[i]);
        st8(hb1 + (cur ^ 1) * (64 * 512) + ob * 512 + c0 + oc, __builtin_bit_cast(u32x2, hv));
      }
      cur ^= 1;
      tgt += 32;
      if (t != 511) gbarA(bar1, tgt);
      // prefetch ys0(t+1) into the SAME yl registers (dead after phase-2 MFMAs):
      // poll prog (producer is ahead -> usually first-hit), then issue; drains at
      // next step's phase-1 waitv0, overlapped with output stores + hl loads.
      if (t != 511) {
        if (tid == 0) {
          int pv, it = 0;
          do {
            pv = __hip_atomic_load(prog, __ATOMIC_RELAXED, __HIP_MEMORY_SCOPE_AGENT);
            if (pv > t + 1) break;
            __builtin_amdgcn_s_sleep(2);
          } while (++it < (1 << 20));
        }
        __syncthreads();
        __builtin_amdgcn_sched_barrier(0);
#pragma unroll
        for (int ks = 0; ks < 4; ++ks)
#pragma unroll
          for (int mf = 0; mf < 4; ++mf)
            yl[ks][mf] = ld16c(ys0 + ((size_t)(mf * 16 + lan15) * 512 + (t + 1)) * 512 + kw + ks * 32 + ke8);
      }
      // outputs post-barrier: peers never wait on these acks
      f32x4 o = {hn[0], hn[1], hn[2], hn[3]};
      st16(out_f32 + ((size_t)ob * 512 + t) * 512 + c0 + oc, __builtin_bit_cast(u32x4, o));
      if (t == 511) {
        float* f = finals + (size_t)(ob * 2 + 1) * 512 + c0 + oc;
#pragma unroll
        for (int i = 0; i < 4; ++i) f[i] = hn[i];
      }
    }
  }
}

template <int GXBF>
static void run_all(const float* x, const float* h, const float* Wr, const float* br,
                    const float* Wz, const float* bz, const float* Wh, const float* bh,
                    float* out, char* ws, hipStream_t stream) {
  int* sync  = (int*)(ws + OFF_SYNC);
  u16* hbAll = (u16*)(ws + OFF_HB);
  u16* rhb0  = (u16*)(ws + OFF_RHB0);
  u16* rhb1  = (u16*)(ws + OFF_RHB1);
  u16* WT    = (u16*)(ws + OFF_WT);
  u16* ys0   = (u16*)(ws + OFF_YS0);
  void* gx   = (void*)(ws + OFF_GX);
  float* finals = out + 16777216;

  init_kernel<<<64, 256, 0, stream>>>(h, hbAll, sync);
  convert_w_kernel<<<12288, 256, 0, stream>>>(Wr, Wz, Wh, WT);
  proj_kernel<GXBF><<<3072, 256, 0, stream>>>(x, WT, br, bz, bh, gx);
  gru_pipe<GXBF><<<256, 256, 0, stream>>>(gx, WT, h, hbAll, rhb0, rhb1, ys0,
                                          br, bz, bh, out, finals, sync);
}

extern "C" void kernel_launch(void* const* d_in, const int* in_sizes, int n_in,
                              void* d_out, int out_size, void* d_ws, size_t ws_size,
                              hipStream_t stream) {
  const float* x  = (const float*)d_in[0];
  const float* h  = (const float*)d_in[1];
  const float* Wr = (const float*)d_in[2];
  const float* br = (const float*)d_in[3];
  const float* Wz = (const float*)d_in[4];
  const float* bz = (const float*)d_in[5];
  const float* Wh = (const float*)d_in[6];
  const float* bh = (const float*)d_in[7];
  float* out = (float*)d_out;
  char* ws = (char*)d_ws;

  const size_t need_f32 = OFF_GX + GX_ELEMS * 4;   // 241,546,752 B (230.4 MiB)
  const size_t need_bf  = OFF_GX + GX_ELEMS * 2;   // 140,883,456 B (134.3 MiB)

  if (ws_size >= need_f32) {
    run_all<0>(x, h, Wr, br, Wz, bz, Wh, bh, out, ws, stream);
  } else if (ws_size >= need_bf) {
    run_all<1>(x, h, Wr, br, Wz, bz, Wh, bh, out, ws, stream);
  } else {
    sentinel_kernel<<<1, 64, 0, stream>>>(out, (float)ws_size);
  }
}

// Round 12
// 4925.050 us; speedup vs baseline: 1.6687x; 1.0616x over previous
//
#include <hip/hip_runtime.h>

typedef unsigned int uint;
typedef unsigned short u16;
typedef short s16x8 __attribute__((ext_vector_type(8)));
typedef float f32x4 __attribute__((ext_vector_type(4)));
typedef uint u32x4 __attribute__((ext_vector_type(4)));
typedef uint u32x2 __attribute__((ext_vector_type(2)));

#define MFMA16(a, b, c) __builtin_amdgcn_mfma_f32_16x16x32_bf16((a), (b), (c), 0, 0, 0)

// ---- problem constants ----
// B=64, S=512, D=512, H=512, L=2
static const size_t OFF_SYNC = 0;                      // 1024 B
static const size_t OFF_HB   = 1024;                   // [2 layers][2 bufs][64][512] bf16 = 262144
static const size_t OFF_RHB0 = 263168;                 // [64][512] bf16 = 65536
static const size_t OFF_RHB1 = 328704;                 // [64][512] bf16 = 65536
static const size_t OFF_WT   = 394240;                 // [2][3][512][1024] bf16 = 6291456
static const size_t OFF_YS0  = 6685696;                // [64][512][512] bf16 = 33554432
static const size_t OFF_GX   = 40240128;               // [512][64][1536] f32 or bf16 (layer 0 only)
static const size_t GX_ELEMS = (size_t)512 * 64 * 1536;

__device__ __forceinline__ short f2bf(float x) {       // RNE float->bf16
  uint u = __builtin_bit_cast(uint, x);
  u = u + 0x7fffu + ((u >> 16) & 1u);
  return (short)(u >> 16);
}
__device__ __forceinline__ float bf2f(u16 v) {
  uint u = ((uint)v) << 16;
  return __builtin_bit_cast(float, u);
}

// ---- raw memory ops ----
__device__ __forceinline__ u32x4 ld16(const void* p) {          // plain: L1 + local L2
  u32x4 r;
  asm volatile("global_load_dwordx4 %0, %1, off" : "=v"(r) : "v"(p));
  return r;
}
__device__ __forceinline__ u32x2 ld8(const void* p) {
  u32x2 r;
  asm volatile("global_load_dwordx2 %0, %1, off" : "=v"(r) : "v"(p));
  return r;
}
__device__ __forceinline__ void st16(void* p, u32x4 v) {
  asm volatile("global_store_dwordx4 %0, %1, off" :: "v"(p), "v"(v));
}
__device__ __forceinline__ void st8(void* p, u32x2 v) {
  asm volatile("global_store_dwordx2 %0, %1, off" :: "v"(p), "v"(v));
}
// cross-XCD coherent (system scope, served at L3): sc0 sc1 — R3-proven combo
__device__ __forceinline__ u32x4 ld16c(const void* p) {
  u32x4 r;
  asm volatile("global_load_dwordx4 %0, %1, off sc0 sc1" : "=v"(r) : "v"(p));
  return r;
}
__device__ __forceinline__ void st8c(void* p, u32x2 v) {
  asm volatile("global_store_dwordx2 %0, %1, off sc0 sc1" :: "v"(p), "v"(v));
}
__device__ __forceinline__ void waitv0() {
  asm volatile("s_waitcnt vmcnt(0)" ::: "memory");
  __builtin_amdgcn_sched_barrier(0);   // rule #18
}

// ---------------- sentinel ----------------
__global__ void sentinel_kernel(float* __restrict__ out, float v) {
  out[threadIdx.x] = v;
}

// ---------------- init: sync words, h0 -> bf16 ----------------
__global__ void init_kernel(const float* __restrict__ h_in, u16* __restrict__ hb,
                            int* __restrict__ sync) {
  int idx = blockIdx.x * 256 + threadIdx.x;
  if (idx < 256) sync[idx] = (idx == 80 || idx == 81) ? -1 : 0;   // winners = -1
  for (int i = idx; i < 2 * 64 * 512; i += gridDim.x * 256) {
    int l = i >> 15, b = (i >> 9) & 63, c = i & 511;
    hb[l * 65536 + b * 512 + c] = (u16)f2bf(h_in[(b * 2 + l) * 512 + c]);
  }
}

// ---------------- W (L,1024,512) f32 -> WT[l][g][n][k] bf16 (k-major) ----------------
__global__ void convert_w_kernel(const float* __restrict__ Wr, const float* __restrict__ Wz,
                                 const float* __restrict__ Wh, u16* __restrict__ WT) {
  int idx = blockIdx.x * 256 + threadIdx.x;       // 6*512*1024 = 3145728 total
  int n = idx & 511, k = (idx >> 9) & 1023, lg = idx >> 19;
  int l = (lg >= 3) ? 1 : 0, g = lg - l * 3;
  const float* W = (g == 0 ? Wr : (g == 1 ? Wz : Wh)) + (size_t)l * 1024 * 512;
  WT[((size_t)lg * 512 + n) * 1024 + k] = (u16)f2bf(W[k * 512 + n]);
}

// ---------------- input projection GEMM (layer 0 only) ----------------
template <int GXBF>
__global__ __launch_bounds__(256) void proj_kernel(
    const float* __restrict__ A, const u16* __restrict__ WT,
    const float* __restrict__ br, const float* __restrict__ bz, const float* __restrict__ bh,
    void* __restrict__ gx) {
  __shared__ u16 Alds[128 * 64];
  __shared__ u16 Blds[128 * 64];
  const int tid = threadIdx.x;
  const int wave = tid >> 6, lane = tid & 63;
  const int lan15 = lane & 15, lanhi = lane >> 4;
  const int mb = blockIdx.x & 255, nb = blockIdx.x >> 8;
  const int m0 = mb * 128, n0 = nb * 128;
  const int wm = (wave >> 1) * 64, wn = (wave & 1) * 64;

  const f32x4 z4 = {0.f, 0.f, 0.f, 0.f};
  f32x4 acc[4][4];
#pragma unroll
  for (int i = 0; i < 4; ++i)
#pragma unroll
    for (int j = 0; j < 4; ++j) acc[i][j] = z4;

  for (int kb = 0; kb < 512; kb += 64) {
    __syncthreads();
#pragma unroll
    for (int p = 0; p < 4; ++p) {        // stage+convert A tile 128x64 (XOR-swizzled 16B slots)
      int idx = p * 256 + tid;
      int row = idx >> 3, slot = idx & 7;
      const float* src = A + (size_t)(m0 + row) * 512 + kb + slot * 8;
      float4 v0 = *(const float4*)src;
      float4 v1 = *(const float4*)(src + 4);
      u16 tmp[8] = {(u16)f2bf(v0.x), (u16)f2bf(v0.y), (u16)f2bf(v0.z), (u16)f2bf(v0.w),
                    (u16)f2bf(v1.x), (u16)f2bf(v1.y), (u16)f2bf(v1.z), (u16)f2bf(v1.w)};
      *(uint4*)((char*)Alds + row * 128 + ((slot ^ (row & 7)) * 16)) = *(uint4*)tmp;
    }
#pragma unroll
    for (int p = 0; p < 4; ++p) {        // stage B tile 128x64 from WT (n-major rows)
      int idx = p * 256 + tid;
      int row = idx >> 3, slot = idx & 7;
      int ng = n0 + row, g = ng >> 9, nc = ng & 511;
      uint4 v = *(const uint4*)(WT + ((size_t)g * 512 + nc) * 1024 + kb + slot * 8);
      *(uint4*)((char*)Blds + row * 128 + ((slot ^ (row & 7)) * 16)) = v;
    }
    __syncthreads();
#pragma unroll
    for (int ks = 0; ks < 2; ++ks) {
      s16x8 af[4], bfr[4];
#pragma unroll
      for (int f = 0; f < 4; ++f) {
        int rowA = wm + f * 16 + lan15;
        af[f] = *(const s16x8*)((const char*)Alds + rowA * 128 + (((ks * 4 + lanhi) ^ (rowA & 7)) * 16));
        int rowB = wn + f * 16 + lan15;
        bfr[f] = *(const s16x8*)((const char*)Blds + rowB * 128 + (((ks * 4 + lanhi) ^ (rowB & 7)) * 16));
      }
#pragma unroll
      for (int mf = 0; mf < 4; ++mf)
#pragma unroll
        for (int nf = 0; nf < 4; ++nf)
          acc[mf][nf] = MFMA16(af[mf], bfr[nf], acc[mf][nf]);
    }
  }
#pragma unroll
  for (int nf = 0; nf < 4; ++nf) {
    int n = n0 + wn + nf * 16 + lan15;
    int g = n >> 9, nc = n & 511;
    float bias = (g == 0 ? br[nc] : (g == 1 ? bz[nc] : bh[nc]));
#pragma unroll
    for (int mf = 0; mf < 4; ++mf) {
#pragma unroll
      for (int q = 0; q < 4; ++q) {
        int m = m0 + wm + mf * 16 + lanhi * 4 + q;
        int s = m & 511, b = m >> 9;
        size_t e = (size_t)(s * 64 + b) * 1536 + n;
        float v = acc[mf][nf][q] + bias;
        if constexpr (GXBF) ((u16*)gx)[e] = (u16)f2bf(v);
        else ((float*)gx)[e] = v;
      }
    }
  }
}

// ---------------- XCD-local barrier: L2-executed atomics (R6/R7-proven) ----------------
__device__ __forceinline__ void gbarA(int* bar, int target) {
  asm volatile("s_waitcnt vmcnt(0)" ::: "memory");
  __syncthreads();
  if (threadIdx.x == 0) {
    int one = 1;
    asm volatile("global_atomic_add %0, %1, off" :: "v"(bar), "v"(one) : "memory");
    int v, zero = 0, iter = 0;
    do {
      __builtin_amdgcn_s_sleep(1);
      asm volatile("global_atomic_add %0, %1, %2, off sc0\n\ts_waitcnt vmcnt(0)"
                   : "=v"(v) : "v"(bar), "v"(zero) : "memory");
    } while (v < target && ++iter < (1 << 17));      // watchdog
  }
  __syncthreads();
  __builtin_amdgcn_sched_barrier(0);
}

// split arrive/wait halves (consumer): independent work goes between them
__device__ __forceinline__ void bar_arrive(int* bar) {
  asm volatile("s_waitcnt vmcnt(0)" ::: "memory");   // my publishes are in L2
  __syncthreads();
  if (threadIdx.x == 0) {
    int one = 1;
    asm volatile("global_atomic_add %0, %1, off" :: "v"(bar), "v"(one) : "memory");
  }
}
__device__ __forceinline__ void bar_wait(int* bar, int target) {
  if (threadIdx.x == 0) {
    int v, zero = 0, iter = 0;
    do {
      __builtin_amdgcn_s_sleep(1);
      asm volatile("global_atomic_add %0, %1, %2, off sc0\n\ts_waitcnt vmcnt(0)"
                   : "=v"(v) : "v"(bar), "v"(zero) : "memory");
    } while (v < target && ++iter < (1 << 17));      // watchdog
  }
  __syncthreads();
  __builtin_amdgcn_sched_barrier(0);
}

// red buffer: [4 waves][48 cols][64 batches] f32 (r | z | w1h blocks), XOR-swizzled
__device__ __forceinline__ int red_off48(int w, int c, int b) {
  return ((w * 48 + c) << 6) + ((((b >> 2) ^ (c & 15)) & 15) << 2) + (b & 3);
}

template <int GXBF>
__device__ __forceinline__ void unpack4(const u32x4& a4, const u32x2& a2, float o[4]) {
  if constexpr (GXBF) {
    const u16* p = (const u16*)&a2;
#pragma unroll
    for (int i = 0; i < 4; ++i) o[i] = bf2f(p[i]);
  } else {
    const float* p = (const float*)&a4;
#pragma unroll
    for (int i = 0; i < 4; ++i) o[i] = p[i];
  }
}

// ---------------- persistent pipelined GRU: both layers concurrently ----------------
// grid=256, 84KB LDS -> 1 WG/CU -> each XCD hosts exactly 32 WGs.
// winner0 XCD = layer 0 producer (R9-proven loop, untouched).
// winner1 XCD = layer 1 consumer: ALL THREE ys0(t) contributions (W1r, W1z, W1h) are
// computed in phase 1 (the W1h term is independent of r and passes through red block 2),
// so phase 2 never reads yl -> yl(t+1) prefetch into the same registers is safe, issued
// between bar_arrive and bar_wait of barrier 1. Output stores overlap barrier 2.
// prog polls amortized via LDS-cached s_prog.
template <int GXBF>
__global__ __launch_bounds__(256, 1) void gru_pipe(
    const void* __restrict__ gx,     // [512][64][1536] layer-0 gates
    const u16* __restrict__ WT,      // [2][3][512][1024]
    const float* __restrict__ h_in,  // [64][2][512]
    u16* __restrict__ hb,            // [2 layers][2 bufs][64][512]
    u16* __restrict__ rhb0, u16* __restrict__ rhb1,
    u16* __restrict__ ys0,           // [64][512][512] bf16 (L0 -> L1 handoff via L3)
    const float* __restrict__ br, const float* __restrict__ bz, const float* __restrict__ bh,
    float* __restrict__ out_f32,     // d_out [64][512][512] f32
    float* __restrict__ finals,      // d_out + B*S*H  [64][2][512]
    int* __restrict__ sync) {
  __shared__ float red[21504];       // 84 KiB: forces 1 WG/CU; 48-col layout uses 49152B? no:
                                     // 4*48*64*4B = 49152 B <= 86016 B. OK.
  __shared__ int s_slot, s_role, s_prog;

  int* bar0 = sync + 0;
  int* bar1 = sync + 32;
  int* claim = sync + 64;
  int* winner0 = sync + 80;
  int* winner1 = sync + 81;
  int* prog = sync + 96;

  // ---- election: two winner XCDs ----
  if (threadIdx.x == 0) {
    int xcc;
    asm volatile("s_getreg_b32 %0, hwreg(HW_REG_XCC_ID)" : "=s"(xcc));
    xcc &= 7;
    int slot = __hip_atomic_fetch_add(&claim[xcc], 1, __ATOMIC_RELAXED, __HIP_MEMORY_SCOPE_AGENT);
    if (slot == 31) {
      int exp = -1;
      bool ok = __hip_atomic_compare_exchange_strong(winner0, &exp, xcc, __ATOMIC_RELAXED,
                                                     __ATOMIC_RELAXED, __HIP_MEMORY_SCOPE_AGENT);
      if (!ok) {
        exp = -1;
        __hip_atomic_compare_exchange_strong(winner1, &exp, xcc, __ATOMIC_RELAXED,
                                             __ATOMIC_RELAXED, __HIP_MEMORY_SCOPE_AGENT);
      }
    }
    int w0, w1, it = 0;
    do {
      __builtin_amdgcn_s_sleep(8);
      w0 = __hip_atomic_load(winner0, __ATOMIC_RELAXED, __HIP_MEMORY_SCOPE_AGENT);
      w1 = __hip_atomic_load(winner1, __ATOMIC_RELAXED, __HIP_MEMORY_SCOPE_AGENT);
    } while ((w0 < 0 || w1 < 0) && ++it < (1 << 22));
    int role = -1;
    if (slot < 32) {
      if (xcc == w0) role = 0;
      else if (xcc == w1) role = 1;
    }
    s_slot = slot;
    s_role = role;
    s_prog = 0;
  }
  __syncthreads();
  const int slot = s_slot, role = s_role;
  if (role < 0) return;

  const int tid = threadIdx.x;
  const int wave = tid >> 6, lane = tid & 63;
  const int lan15 = lane & 15, lanhi = lane >> 4;
  const int c0 = slot * 16;
  const int kw = wave * 128;
  const int ke8 = lanhi * 8;
  const int ob = tid >> 2, oc = (tid & 3) * 4;
  const int ES = GXBF ? 2 : 4;
  const f32x4 z4 = {0.f, 0.f, 0.f, 0.f};

  if (role == 0) {
    // ================= LAYER 0 (producer) — R9-proven loop, red_off48 relayout only =====
    const u16* WT0 = WT;
    u16* hb0 = hb;
    s16x8 wrz[2][4], whh[4];
#pragma unroll
    for (int g = 0; g < 2; ++g)
#pragma unroll
      for (int ks = 0; ks < 4; ++ks)
        wrz[g][ks] = *(const s16x8*)(WT0 + ((size_t)(g * 512 + c0 + lan15)) * 1024 + 512 + kw + ks * 32 + ke8);
#pragma unroll
    for (int ks = 0; ks < 4; ++ks)
      whh[ks] = *(const s16x8*)(WT0 + ((size_t)(1024 + c0 + lan15)) * 1024 + 512 + kw + ks * 32 + ke8);

    float hown[4];
#pragma unroll
    for (int i = 0; i < 4; ++i) hown[i] = h_in[(ob * 2 + 0) * 512 + c0 + oc + i];

    u32x4 pf_r4 = {0,0,0,0}, pf_z4 = {0,0,0,0}, pf_hc4 = {0,0,0,0}, pf_hn4 = {0,0,0,0};
    u32x2 pf_r2 = {0,0}, pf_z2 = {0,0}, pf_hc2 = {0,0}, pf_hn2 = {0,0};
    auto issue_pf = [&](int tp) {
      const char* gq = (const char*)gx + ((size_t)(tp * 64 + ob) * 1536 + c0 + oc) * ES;
      if constexpr (GXBF) {
        pf_r2 = ld8(gq); pf_z2 = ld8(gq + 1024); pf_hn2 = ld8(gq + 2048);
      } else {
        pf_r4 = ld16(gq); pf_z4 = ld16(gq + 2048); pf_hn4 = ld16(gq + 4096);
      }
    };
    issue_pf(0);

    int cur = 0, tgt = 0;
    for (int t = 0; t < 512; ++t) {
      const u16* hcur = hb0 + cur * (64 * 512);
      u32x4 hl[4][4];
#pragma unroll
      for (int ks = 0; ks < 4; ++ks)
#pragma unroll
        for (int mf = 0; mf < 4; ++mf)
          hl[ks][mf] = ld16(hcur + (mf * 16 + lan15) * 512 + kw + ks * 32 + ke8);
      waitv0();
      f32x4 acc[4][2];
#pragma unroll
      for (int i = 0; i < 4; ++i) { acc[i][0] = z4; acc[i][1] = z4; }
#pragma unroll
      for (int ks = 0; ks < 4; ++ks)
#pragma unroll
        for (int mf = 0; mf < 4; ++mf) {
          s16x8 af = __builtin_bit_cast(s16x8, hl[ks][mf]);
          acc[mf][0] = MFMA16(af, wrz[0][ks], acc[mf][0]);
          acc[mf][1] = MFMA16(af, wrz[1][ks], acc[mf][1]);
        }
#pragma unroll
      for (int mf = 0; mf < 4; ++mf)
#pragma unroll
        for (int g = 0; g < 2; ++g)
          *(f32x4*)(red + red_off48(wave, g * 16 + lan15, mf * 16 + lanhi * 4)) = acc[mf][g];
      __syncthreads();
      float zg[4];
      {
        float grf[4], gzf[4];
        unpack4<GXBF>(pf_r4, pf_r2, grf);
        unpack4<GXBF>(pf_z4, pf_z2, gzf);
        u16 rh[4];
#pragma unroll
        for (int i = 0; i < 4; ++i) {
          float rp = grf[i], zp = gzf[i];
#pragma unroll
          for (int w = 0; w < 4; ++w) {
            rp += red[red_off48(w, oc + i, ob)];
            zp += red[red_off48(w, 16 + oc + i, ob)];
          }
          float r = 1.f / (1.f + __expf(-rp));
          zg[i] = 1.f / (1.f + __expf(-zp));
          rh[i] = (u16)f2bf(r * hown[i]);
        }
        st8(rhb0 + ob * 512 + c0 + oc, __builtin_bit_cast(u32x2, rh));
      }
      tgt += 32; gbarA(bar0, tgt);
      pf_hc4 = pf_hn4; pf_hc2 = pf_hn2;
      u32x4 rl[4][4];
#pragma unroll
      for (int ks = 0; ks < 4; ++ks)
#pragma unroll
        for (int mf = 0; mf < 4; ++mf)
          rl[ks][mf] = ld16(rhb0 + (mf * 16 + lan15) * 512 + kw + ks * 32 + ke8);
      issue_pf(t < 511 ? t + 1 : 511);
      asm volatile("s_waitcnt vmcnt(3)" ::: "memory");
      __builtin_amdgcn_sched_barrier(0);
      f32x4 acc2[4];
#pragma unroll
      for (int i = 0; i < 4; ++i) acc2[i] = z4;
#pragma unroll
      for (int ks = 0; ks < 4; ++ks)
#pragma unroll
        for (int mf = 0; mf < 4; ++mf)
          acc2[mf] = MFMA16(__builtin_bit_cast(s16x8, rl[ks][mf]), whh[ks], acc2[mf]);
#pragma unroll
      for (int mf = 0; mf < 4; ++mf)
        *(f32x4*)(red + red_off48(wave, lan15, mf * 16 + lanhi * 4)) = acc2[mf];
      __syncthreads();
      float hn[4];
      u16 hv[4];
      {
        float ghf[4];
        unpack4<GXBF>(pf_hc4, pf_hc2, ghf);
#pragma unroll
        for (int i = 0; i < 4; ++i) {
          float wp = 0.f;
#pragma unroll
          for (int w = 0; w < 4; ++w) wp += red[red_off48(w, oc + i, ob)];
          float pre = ghf[i] + wp;
          pre = fminf(15.f, fmaxf(-15.f, pre));
          float e = __expf(-2.f * pre);
          float ht = (1.f - e) / (1.f + e);
          hn[i] = (1.f - zg[i]) * hown[i] + zg[i] * ht;
          hown[i] = hn[i];
          hv[i] = (u16)f2bf(hn[i]);
        }
        st8(hb0 + (cur ^ 1) * (64 * 512) + ob * 512 + c0 + oc, __builtin_bit_cast(u32x2, hv));
        st8c(ys0 + ((size_t)ob * 512 + t) * 512 + c0 + oc, __builtin_bit_cast(u32x2, hv));
      }
      cur ^= 1;
      tgt += 32;
      gbarA(bar0, tgt);
      if (tid == 0 && slot == 0)
        __hip_atomic_fetch_add(prog, 1, __ATOMIC_RELAXED, __HIP_MEMORY_SCOPE_AGENT);
      if (t == 511) {
        float* f = finals + (size_t)(ob * 2 + 0) * 512 + c0 + oc;
#pragma unroll
        for (int i = 0; i < 4; ++i) f[i] = hn[i];
      }
    }
  } else {
    // ============ LAYER 1 (consumer): all ys0 MFMAs in phase 1; overlapped barriers ======
    const u16* WT1 = WT + (size_t)3 * 512 * 1024;
    u16* hb1 = hb + 2 * 64 * 512;
    s16x8 wrz[2][4], whh[4];
    s16x8 w1rz[2][4], w1h[4];
#pragma unroll
    for (int g = 0; g < 2; ++g)
#pragma unroll
      for (int ks = 0; ks < 4; ++ks) {
        wrz[g][ks]  = *(const s16x8*)(WT1 + ((size_t)(g * 512 + c0 + lan15)) * 1024 + 512 + kw + ks * 32 + ke8);
        w1rz[g][ks] = *(const s16x8*)(WT1 + ((size_t)(g * 512 + c0 + lan15)) * 1024 + kw + ks * 32 + ke8);
      }
#pragma unroll
    for (int ks = 0; ks < 4; ++ks) {
      whh[ks] = *(const s16x8*)(WT1 + ((size_t)(1024 + c0 + lan15)) * 1024 + 512 + kw + ks * 32 + ke8);
      w1h[ks] = *(const s16x8*)(WT1 + ((size_t)(1024 + c0 + lan15)) * 1024 + kw + ks * 32 + ke8);
    }
    float brv[4], bzv[4], bhv[4];
#pragma unroll
    for (int i = 0; i < 4; ++i) {
      brv[i] = br[512 + c0 + oc + i];
      bzv[i] = bz[512 + c0 + oc + i];
      bhv[i] = bh[512 + c0 + oc + i];
    }
    float hown[4];
#pragma unroll
    for (int i = 0; i < 4; ++i) hown[i] = h_in[(ob * 2 + 1) * 512 + c0 + oc + i];

    u32x4 yl[4][4];                               // ys0 fragments (single buffer)

    // prologue: wait producer step 0, issue yl(0)
    if (tid == 0) {
      int pv, it = 0;
      do {
        pv = __hip_atomic_load(prog, __ATOMIC_RELAXED, __HIP_MEMORY_SCOPE_AGENT);
        if (pv > 0) break;
        __builtin_amdgcn_s_sleep(2);
      } while (++it < (1 << 20));
      s_prog = pv;
    }
    __syncthreads();
    __builtin_amdgcn_sched_barrier(0);
#pragma unroll
    for (int ks = 0; ks < 4; ++ks)
#pragma unroll
      for (int mf = 0; mf < 4; ++mf)
        yl[ks][mf] = ld16c(ys0 + ((size_t)(mf * 16 + lan15) * 512 + 0) * 512 + kw + ks * 32 + ke8);

    int cur = 0, tgt = 0;
    for (int t = 0; t < 512; ++t) {
      const u16* hcur = hb1 + cur * (64 * 512);
      u32x4 hl[4][4];
#pragma unroll
      for (int ks = 0; ks < 4; ++ks)
#pragma unroll
        for (int mf = 0; mf < 4; ++mf)
          hl[ks][mf] = ld16(hcur + (mf * 16 + lan15) * 512 + kw + ks * 32 + ke8);
      waitv0();                                  // hl + prefetched yl retired
      // phase 1: r-gate, z-gate AND the ys0@W1h term (3 blocks of 16 cols)
      f32x4 acc[4][3];
#pragma unroll
      for (int i = 0; i < 4; ++i) { acc[i][0] = z4; acc[i][1] = z4; acc[i][2] = z4; }
#pragma unroll
      for (int ks = 0; ks < 4; ++ks)
#pragma unroll
        for (int mf = 0; mf < 4; ++mf) {
          s16x8 ah = __builtin_bit_cast(s16x8, hl[ks][mf]);
          s16x8 ay = __builtin_bit_cast(s16x8, yl[ks][mf]);
          acc[mf][0] = MFMA16(ah, wrz[0][ks], acc[mf][0]);
          acc[mf][0] = MFMA16(ay, w1rz[0][ks], acc[mf][0]);
          acc[mf][1] = MFMA16(ah, wrz[1][ks], acc[mf][1]);
          acc[mf][1] = MFMA16(ay, w1rz[1][ks], acc[mf][1]);
          acc[mf][2] = MFMA16(ay, w1h[ks], acc[mf][2]);
        }
#pragma unroll
      for (int mf = 0; mf < 4; ++mf)
#pragma unroll
        for (int g = 0; g < 3; ++g)
          *(f32x4*)(red + red_off48(wave, g * 16 + lan15, mf * 16 + lanhi * 4)) = acc[mf][g];
      __syncthreads();
      float zg[4], w1c[4];
      {
        u16 rh[4];
#pragma unroll
        for (int i = 0; i < 4; ++i) {
          float rp = brv[i], zp = bzv[i], wc = 0.f;
#pragma unroll
          for (int w = 0; w < 4; ++w) {
            rp += red[red_off48(w, oc + i, ob)];
            zp += red[red_off48(w, 16 + oc + i, ob)];
            wc += red[red_off48(w, 32 + oc + i, ob)];
          }
          float r = 1.f / (1.f + __expf(-rp));
          zg[i] = 1.f / (1.f + __expf(-zp));
          w1c[i] = wc;                           // ys0(t)@W1h, carried to phase 2
          rh[i] = (u16)f2bf(r * hown[i]);
        }
        st8(rhb1 + ob * 512 + c0 + oc, __builtin_bit_cast(u32x2, rh));
      }
      // ---- barrier 1 split: arrive -> (prog check + yl(t+1) issue) -> wait ----
      tgt += 32;
      bar_arrive(bar1);
      if (t != 511) {
        if (s_prog < t + 2) {                    // uniform (s_prog stable since last sync)
          if (tid == 0) {
            int pv, it = 0;
            do {
              pv = __hip_atomic_load(prog, __ATOMIC_RELAXED, __HIP_MEMORY_SCOPE_AGENT);
              if (pv >= t + 2) break;
              __builtin_amdgcn_s_sleep(2);
            } while (++it < (1 << 20));
            s_prog = pv;
          }
          __syncthreads();
        }
#pragma unroll
        for (int ks = 0; ks < 4; ++ks)
#pragma unroll
          for (int mf = 0; mf < 4; ++mf)
            yl[ks][mf] = ld16c(ys0 + ((size_t)(mf * 16 + lan15) * 512 + (t + 1)) * 512 + kw + ks * 32 + ke8);
      }
      bar_wait(bar1, tgt);
      // phase 2: (r*h)@Whh only; yl not read (its W1h term came through red block 2)
      u32x4 rl[4][4];
#pragma unroll
      for (int ks = 0; ks < 4; ++ks)
#pragma unroll
        for (int mf = 0; mf < 4; ++mf)
          rl[ks][mf] = ld16(rhb1 + (mf * 16 + lan15) * 512 + kw + ks * 32 + ke8);
      waitv0();                                  // drains rl AND yl(t+1) prefetch
      f32x4 acc2[4];
#pragma unroll
      for (int i = 0; i < 4; ++i) acc2[i] = z4;
#pragma unroll
      for (int ks = 0; ks < 4; ++ks)
#pragma unroll
        for (int mf = 0; mf < 4; ++mf)
          acc2[mf] = MFMA16(__builtin_bit_cast(s16x8, rl[ks][mf]), whh[ks], acc2[mf]);
#pragma unroll
      for (int mf = 0; mf < 4; ++mf)
        *(f32x4*)(red + red_off48(wave, lan15, mf * 16 + lanhi * 4)) = acc2[mf];
      __syncthreads();
      float hn[4];
      {
#pragma unroll
        for (int i = 0; i < 4; ++i) {
          float wp = bhv[i] + w1c[i];
#pragma unroll
          for (int w = 0; w < 4; ++w) wp += red[red_off48(w, oc + i, ob)];
          float pre = fminf(15.f, fmaxf(-15.f, wp));
          float e = __expf(-2.f * pre);
          float ht = (1.f - e) / (1.f + e);
          hn[i] = (1.f - zg[i]) * hown[i] + zg[i] * ht;
          hown[i] = hn[i];
        }
        u16 hv[4];
#pragma unroll
        for (int i = 0; i < 4; ++i) hv[i] = (u16)f2bf(hn[i]);
        st8(hb1 + ((t & 1) ^ 1) * (64 * 512) + ob * 512 + c0 + oc, __builtin_bit_cast(u32x2, hv));
      }
      // ---- barrier 2 split: arrive -> output stores -> wait ----
      tgt += 32;
      if (t != 511) {
        bar_arrive(bar1);
        f32x4 o = {hn[0], hn[1], hn[2], hn[3]};
        st16(out_f32 + ((size_t)ob * 512 + t) * 512 + c0 + oc, __builtin_bit_cast(u32x4, o));
        bar_wait(bar1, tgt);
      } else {
        f32x4 o = {hn[0], hn[1], hn[2], hn[3]};
        st16(out_f32 + ((size_t)ob * 512 + t) * 512 + c0 + oc, __builtin_bit_cast(u32x4, o));
        float* f = finals + (size_t)(ob * 2 + 1) * 512 + c0 + oc;
#pragma unroll
        for (int i = 0; i < 4; ++i) f[i] = hn[i];
      }
      cur ^= 1;
    }
  }
}

template <int GXBF>
static void run_all(const float* x, const float* h, const float* Wr, const float* br,
                    const float* Wz, const float* bz, const float* Wh, const float* bh,
                    float* out, char* ws, hipStream_t stream) {
  int* sync  = (int*)(ws + OFF_SYNC);
  u16* hbAll = (u16*)(ws + OFF_HB);
  u16* rhb0  = (u16*)(ws + OFF_RHB0);
  u16* rhb1  = (u16*)(ws + OFF_RHB1);
  u16* WT    = (u16*)(ws + OFF_WT);
  u16* ys0   = (u16*)(ws + OFF_YS0);
  void* gx   = (void*)(ws + OFF_GX);
  float* finals = out + 16777216;

  init_kernel<<<64, 256, 0, stream>>>(h, hbAll, sync);
  convert_w_kernel<<<12288, 256, 0, stream>>>(Wr, Wz, Wh, WT);
  proj_kernel<GXBF><<<3072, 256, 0, stream>>>(x, WT, br, bz, bh, gx);
  gru_pipe<GXBF><<<256, 256, 0, stream>>>(gx, WT, h, hbAll, rhb0, rhb1, ys0,
                                          br, bz, bh, out, finals, sync);
}

extern "C" void kernel_launch(void* const* d_in, const int* in_sizes, int n_in,
                              void* d_out, int out_size, void* d_ws, size_t ws_size,
                              hipStream_t stream) {
  const float* x  = (const float*)d_in[0];
  const float* h  = (const float*)d_in[1];
  const float* Wr = (const float*)d_in[2];
  const float* br = (const float*)d_in[3];
  const float* Wz = (const float*)d_in[4];
  const float* bz = (const float*)d_in[5];
  const float* Wh = (const float*)d_in[6];
  const float* bh = (const float*)d_in[7];
  float* out = (float*)d_out;
  char* ws = (char*)d_ws;

  const size_t need_f32 = OFF_GX + GX_ELEMS * 4;   // 241,546,752 B (230.4 MiB)
  const size_t need_bf  = OFF_GX + GX_ELEMS * 2;   // 140,883,456 B (134.3 MiB)

  if (ws_size >= need_f32) {
    run_all<0>(x, h, Wr, br, Wz, bz, Wh, bh, out, ws, stream);
  } else if (ws_size >= need_bf) {
    run_all<1>(x, h, Wr, br, Wz, bz, Wh, bh, out, ws, stream);
  } else {
    sentinel_kernel<<<1, 64, 0, stream>>>(out, (float)ws_size);
  }
}

// Round 14
// 2422.558 us; speedup vs baseline: 3.3924x; 2.0330x over previous
//
#include <hip/hip_runtime.h>

typedef unsigned int uint;
typedef unsigned short u16;
typedef short s16x8 __attribute__((ext_vector_type(8)));
typedef float f32x4 __attribute__((ext_vector_type(4)));
typedef uint u32x4 __attribute__((ext_vector_type(4)));

#define MFMA16(a, b, c) __builtin_amdgcn_mfma_f32_16x16x32_bf16((a), (b), (c), 0, 0, 0)

// ---- problem constants ----
// B=64, S=512, D=512, H=512, L=2
// sync region (512 ints = 2048 B):
//   [xcc*32], xcc=0..7 : per-XCD barrier counters (own 128B line each)
//   [256..263]         : claim[8] (L3 agent atomics)
//   [320+q*32], q=0..3 : prog[q] (own 128B line each, L3 agent atomics)
// hb/rhb are 4-deep ROTATING buffers (buf = t&3): reuse distance 4 steps keeps
// plain-load L1 lines evicted by capacity (R13's 1-2 step reuse at ~32KB/step
// footprint let L1 serve stale exchange data -> absmax 6e-2).
static const size_t OFF_SYNC = 0;                      // 2048 B
static const size_t OFF_HB   = 2048;                   // [2][4][4 bufs][16][512] bf16 = 524288
static const size_t OFF_RHB  = 526336;                 // [2][4][4 bufs][16][512] bf16 = 524288
static const size_t OFF_WT   = 1050624;                // [2][3][512][1024] bf16 = 6291456
static const size_t OFF_YS0  = 7342080;                // [64][512][512] bf16 = 33554432
static const size_t OFF_GX   = 40896512;               // [512][64][1536] f32 or bf16
static const size_t GX_ELEMS = (size_t)512 * 64 * 1536;

__device__ __forceinline__ short f2bf(float x) {       // RNE float->bf16
  uint u = __builtin_bit_cast(uint, x);
  u = u + 0x7fffu + ((u >> 16) & 1u);
  return (short)(u >> 16);
}
__device__ __forceinline__ float bf2f(u16 v) {
  uint u = ((uint)v) << 16;
  return __builtin_bit_cast(float, u);
}

// ---- raw memory ops ----
__device__ __forceinline__ u32x4 ld16(const void* p) {          // plain: L1 + local L2
  u32x4 r;
  asm volatile("global_load_dwordx4 %0, %1, off" : "=v"(r) : "v"(p));
  return r;
}
__device__ __forceinline__ uint ld4u(const void* p) {
  uint r;
  asm volatile("global_load_dword %0, %1, off" : "=v"(r) : "v"(p));
  return r;
}
__device__ __forceinline__ uint ld2x(const void* p) {
  uint r;
  asm volatile("global_load_ushort %0, %1, off" : "=v"(r) : "v"(p));
  return r;
}
__device__ __forceinline__ void st4(void* p, uint v) {
  asm volatile("global_store_dword %0, %1, off" :: "v"(p), "v"(v));
}
__device__ __forceinline__ void st2(void* p, u16 v) {
  uint x = v;
  asm volatile("global_store_short %0, %1, off" :: "v"(p), "v"(x));
}
// cross-XCD coherent (system scope, served at L3): sc0 sc1 — R3/R9-proven combo
__device__ __forceinline__ u32x4 ld16c(const void* p) {
  u32x4 r;
  asm volatile("global_load_dwordx4 %0, %1, off sc0 sc1" : "=v"(r) : "v"(p));
  return r;
}
__device__ __forceinline__ void st2c(void* p, u16 v) {
  uint x = v;
  asm volatile("global_store_short %0, %1, off sc0 sc1" :: "v"(p), "v"(x));
}
__device__ __forceinline__ void waitv0() {
  asm volatile("s_waitcnt vmcnt(0)" ::: "memory");
  __builtin_amdgcn_sched_barrier(0);   // rule #18
}

template <int GXBF>
__device__ __forceinline__ float upk(uint v) {
  if constexpr (GXBF) return bf2f((u16)v);
  else return __builtin_bit_cast(float, v);
}

// ---------------- sentinel ----------------
__global__ void sentinel_kernel(float* __restrict__ out, float v) {
  out[threadIdx.x] = v;
}

// ---------------- init: sync words, h0 -> bf16 quarter layout (buf 0 of 4) ----------------
__global__ void init_kernel(const float* __restrict__ h_in, u16* __restrict__ hb,
                            int* __restrict__ sync) {
  int idx = blockIdx.x * 256 + threadIdx.x;
  if (idx < 512) sync[idx] = 0;
  for (int i = idx; i < 2 * 64 * 512; i += gridDim.x * 256) {
    int l = i >> 15, b = (i >> 9) & 63, c = i & 511;
    int q = b >> 4, ob = b & 15;
    hb[((l * 4 + q) * 4 + 0) * 8192 + ob * 512 + c] = (u16)f2bf(h_in[(b * 2 + l) * 512 + c]);
  }
}

// ---------------- W (L,1024,512) f32 -> WT[l][g][n][k] bf16 (k-major) ----------------
__global__ void convert_w_kernel(const float* __restrict__ Wr, const float* __restrict__ Wz,
                                 const float* __restrict__ Wh, u16* __restrict__ WT) {
  int idx = blockIdx.x * 256 + threadIdx.x;       // 6*512*1024 = 3145728 total
  int n = idx & 511, k = (idx >> 9) & 1023, lg = idx >> 19;
  int l = (lg >= 3) ? 1 : 0, g = lg - l * 3;
  const float* W = (g == 0 ? Wr : (g == 1 ? Wz : Wh)) + (size_t)l * 1024 * 512;
  WT[((size_t)lg * 512 + n) * 1024 + k] = (u16)f2bf(W[k * 512 + n]);
}

// ---------------- input projection GEMM (layer 0 only) ----------------
template <int GXBF>
__global__ __launch_bounds__(256) void proj_kernel(
    const float* __restrict__ A, const u16* __restrict__ WT,
    const float* __restrict__ br, const float* __restrict__ bz, const float* __restrict__ bh,
    void* __restrict__ gx) {
  __shared__ u16 Alds[128 * 64];
  __shared__ u16 Blds[128 * 64];
  const int tid = threadIdx.x;
  const int wave = tid >> 6, lane = tid & 63;
  const int lan15 = lane & 15, lanhi = lane >> 4;
  const int mb = blockIdx.x & 255, nb = blockIdx.x >> 8;
  const int m0 = mb * 128, n0 = nb * 128;
  const int wm = (wave >> 1) * 64, wn = (wave & 1) * 64;

  const f32x4 z4 = {0.f, 0.f, 0.f, 0.f};
  f32x4 acc[4][4];
#pragma unroll
  for (int i = 0; i < 4; ++i)
#pragma unroll
    for (int j = 0; j < 4; ++j) acc[i][j] = z4;

  for (int kb = 0; kb < 512; kb += 64) {
    __syncthreads();
#pragma unroll
    for (int p = 0; p < 4; ++p) {        // stage+convert A tile 128x64 (XOR-swizzled 16B slots)
      int idx = p * 256 + tid;
      int row = idx >> 3, slot = idx & 7;
      const float* src = A + (size_t)(m0 + row) * 512 + kb + slot * 8;
      float4 v0 = *(const float4*)src;
      float4 v1 = *(const float4*)(src + 4);
      u16 tmp[8] = {(u16)f2bf(v0.x), (u16)f2bf(v0.y), (u16)f2bf(v0.z), (u16)f2bf(v0.w),
                    (u16)f2bf(v1.x), (u16)f2bf(v1.y), (u16)f2bf(v1.z), (u16)f2bf(v1.w)};
      *(uint4*)((char*)Alds + row * 128 + ((slot ^ (row & 7)) * 16)) = *(uint4*)tmp;
    }
#pragma unroll
    for (int p = 0; p < 4; ++p) {        // stage B tile 128x64 from WT (n-major rows)
      int idx = p * 256 + tid;
      int row = idx >> 3, slot = idx & 7;
      int ng = n0 + row, g = ng >> 9, nc = ng & 511;
      uint4 v = *(const uint4*)(WT + ((size_t)g * 512 + nc) * 1024 + kb + slot * 8);
      *(uint4*)((char*)Blds + row * 128 + ((slot ^ (row & 7)) * 16)) = v;
    }
    __syncthreads();
#pragma unroll
    for (int ks = 0; ks < 2; ++ks) {
      s16x8 af[4], bfr[4];
#pragma unroll
      for (int f = 0; f < 4; ++f) {
        int rowA = wm + f * 16 + lan15;
        af[f] = *(const s16x8*)((const char*)Alds + rowA * 128 + (((ks * 4 + lanhi) ^ (rowA & 7)) * 16));
        int rowB = wn + f * 16 + lan15;
        bfr[f] = *(const s16x8*)((const char*)Blds + rowB * 128 + (((ks * 4 + lanhi) ^ (rowB & 7)) * 16));
      }
#pragma unroll
      for (int mf = 0; mf < 4; ++mf)
#pragma unroll
        for (int nf = 0; nf < 4; ++nf)
          acc[mf][nf] = MFMA16(af[mf], bfr[nf], acc[mf][nf]);
    }
  }
#pragma unroll
  for (int nf = 0; nf < 4; ++nf) {
    int n = n0 + wn + nf * 16 + lan15;
    int g = n >> 9, nc = n & 511;
    float bias = (g == 0 ? br[nc] : (g == 1 ? bz[nc] : bh[nc]));
#pragma unroll
    for (int mf = 0; mf < 4; ++mf) {
#pragma unroll
      for (int q = 0; q < 4; ++q) {
        int m = m0 + wm + mf * 16 + lanhi * 4 + q;
        int s = m & 511, b = m >> 9;
        size_t e = (size_t)(s * 64 + b) * 1536 + n;
        float v = acc[mf][nf][q] + bias;
        if constexpr (GXBF) ((u16*)gx)[e] = (u16)f2bf(v);
        else ((float*)gx)[e] = v;
      }
    }
  }
}

// ---------------- XCD-local barrier: L2-executed atomics (R6-R12 proven) ----------------
__device__ __forceinline__ void gbarA(int* bar, int target) {
  asm volatile("s_waitcnt vmcnt(0)" ::: "memory");
  __syncthreads();
  if (threadIdx.x == 0) {
    int one = 1;
    asm volatile("global_atomic_add %0, %1, off" :: "v"(bar), "v"(one) : "memory");
    int v, zero = 0, iter = 0;
    do {
      __builtin_amdgcn_s_sleep(1);
      asm volatile("global_atomic_add %0, %1, %2, off sc0\n\ts_waitcnt vmcnt(0)"
                   : "=v"(v) : "v"(bar), "v"(zero) : "memory");
    } while (v < target && ++iter < (1 << 17));      // watchdog
  }
  __syncthreads();
  __builtin_amdgcn_sched_barrier(0);
}
__device__ __forceinline__ void bar_arrive(int* bar) {
  asm volatile("s_waitcnt vmcnt(0)" ::: "memory");
  __syncthreads();
  if (threadIdx.x == 0) {
    int one = 1;
    asm volatile("global_atomic_add %0, %1, off" :: "v"(bar), "v"(one) : "memory");
  }
}
__device__ __forceinline__ void bar_wait(int* bar, int target) {
  if (threadIdx.x == 0) {
    int v, zero = 0, iter = 0;
    do {
      __builtin_amdgcn_s_sleep(1);
      asm volatile("global_atomic_add %0, %1, %2, off sc0\n\ts_waitcnt vmcnt(0)"
                   : "=v"(v) : "v"(bar), "v"(zero) : "memory");
    } while (v < target && ++iter < (1 << 17));      // watchdog
  }
  __syncthreads();
  __builtin_amdgcn_sched_barrier(0);
}

// red: [4 waves][48 cols][pad 20] f32 — stride 20 keeps f32x4 16B-aligned
__device__ __forceinline__ int ROFF(int w, int c, int b) {
  return (w * 48 + c) * 20 + b;
}

// ---------------- persistent pipelined GRU: 8 XCDs = 2 layers x 4 batch-quarters ----------
// grid=256, 84KB LDS -> 1 WG/CU -> each XCD hosts exactly 32 WGs (no election needed).
// Role from HW_REG_XCC_ID: layer = xcc>>2, quarter = xcc&3 (batches 16q..16q+15).
// Producer quarter publishes ys0 (sc0 sc1) + bumps prog[q]; consumer quarter (fused
// input projection) gates on prog[q], prefetches yl in the barrier-1 gap.
// hb/rhb rotate 4-deep (buf = t&3) to defeat stale-L1 reuse (R13 post-mortem).
template <int GXBF>
__global__ __launch_bounds__(256, 1) void gru_pipe(
    const void* __restrict__ gx,     // [512][64][1536] layer-0 gates
    const u16* __restrict__ WT,      // [2][3][512][1024]
    const float* __restrict__ h_in,  // [64][2][512]
    u16* __restrict__ hb,            // [2][4][4 bufs][16][512]
    u16* __restrict__ rhb,           // [2][4][4 bufs][16][512]
    u16* __restrict__ ys0,           // [64][512][512] bf16 (L0 -> L1 via L3)
    const float* __restrict__ br, const float* __restrict__ bz, const float* __restrict__ bh,
    float* __restrict__ out_f32,     // d_out [64][512][512] f32
    float* __restrict__ finals,      // d_out + B*S*H  [64][2][512]
    int* __restrict__ sync) {
  __shared__ float red[21504];       // 84 KiB: forces 1 WG/CU
  __shared__ int s_pack, s_prog;

  if (threadIdx.x == 0) {
    int xcc;
    asm volatile("s_getreg_b32 %0, hwreg(HW_REG_XCC_ID)" : "=s"(xcc));
    xcc &= 7;
    int slot = __hip_atomic_fetch_add(&sync[256 + xcc], 1, __ATOMIC_RELAXED,
                                      __HIP_MEMORY_SCOPE_AGENT);
    s_pack = slot | (xcc << 8);
    s_prog = 0;
  }
  __syncthreads();
  const int slot = s_pack & 255;
  const int xcc  = s_pack >> 8;
  if (slot >= 32) return;

  const int l = (xcc >> 2) & 1, q = xcc & 3;
  int* bar  = sync + xcc * 32;
  int* prog = sync + 320 + q * 32;

  const int tid = threadIdx.x;
  const int wave = tid >> 6, lane = tid & 63;
  const int lan15 = lane & 15, lanhi = lane >> 4;
  const int c0 = slot * 16;          // owned gate/h columns [c0, c0+16)
  const int kw = wave * 128;         // K-split per wave
  const int ke8 = lanhi * 8;
  const int ob = tid >> 4;           // local batch 0..15
  const int col = c0 + (tid & 15);   // owned column (1 per thread)
  const int gb = q * 16 + ob;        // global batch
  const int ES = GXBF ? 2 : 4;
  const f32x4 z4 = {0.f, 0.f, 0.f, 0.f};

  const u16* WTl = WT + (size_t)l * 3 * 512 * 1024;
  u16* hbq  = hb  + (size_t)(l * 4 + q) * 4 * 8192;   // + (t&3)*8192
  u16* rhbq = rhb + (size_t)(l * 4 + q) * 4 * 8192;   // + (t&3)*8192

  // recurrent weights (both roles)
  s16x8 wrz[2][4], whh[4];
#pragma unroll
  for (int g = 0; g < 2; ++g)
#pragma unroll
    for (int ks = 0; ks < 4; ++ks)
      wrz[g][ks] = *(const s16x8*)(WTl + ((size_t)(g * 512 + c0 + lan15)) * 1024 + 512 + kw + ks * 32 + ke8);
#pragma unroll
  for (int ks = 0; ks < 4; ++ks)
    whh[ks] = *(const s16x8*)(WTl + ((size_t)(1024 + c0 + lan15)) * 1024 + 512 + kw + ks * 32 + ke8);

  float hown = h_in[(gb * 2 + l) * 512 + col];

  if (l == 0) {
    // ================= producer quarter (layer 0) =================
    uint pf_r = 0, pf_z = 0, pf_hn = 0, pf_hc = 0;
    auto issue_pf = [&](int tp) {
      const char* gq = (const char*)gx + ((size_t)(tp * 64 + gb) * 1536 + col) * ES;
      if constexpr (GXBF) {
        pf_r = ld2x(gq); pf_z = ld2x(gq + 512 * 2); pf_hn = ld2x(gq + 1024 * 2);
      } else {
        pf_r = ld4u(gq); pf_z = ld4u(gq + 512 * 4); pf_hn = ld4u(gq + 1024 * 4);
      }
    };
    issue_pf(0);

    int tgt = 0;
    for (int t = 0; t < 512; ++t) {
      const u16* hc = hbq + (t & 3) * 8192;
      u16* rhc = rhbq + (t & 3) * 8192;
      u32x4 hl[4];
#pragma unroll
      for (int ks = 0; ks < 4; ++ks)
        hl[ks] = ld16(hc + lan15 * 512 + kw + ks * 32 + ke8);
      waitv0();                                  // hl + pf(t) retired
      f32x4 a0 = z4, a1 = z4;
#pragma unroll
      for (int ks = 0; ks < 4; ++ks) {
        s16x8 ah = __builtin_bit_cast(s16x8, hl[ks]);
        a0 = MFMA16(ah, wrz[0][ks], a0);
        a1 = MFMA16(ah, wrz[1][ks], a1);
      }
      *(f32x4*)(red + ROFF(wave, lan15, lanhi * 4)) = a0;
      *(f32x4*)(red + ROFF(wave, 16 + lan15, lanhi * 4)) = a1;
      __syncthreads();
      float zg;
      {
        float rp = upk<GXBF>(pf_r), zp = upk<GXBF>(pf_z);
#pragma unroll
        for (int w = 0; w < 4; ++w) {
          rp += red[ROFF(w, col - c0, ob)];
          zp += red[ROFF(w, 16 + (col - c0), ob)];
        }
        float r = 1.f / (1.f + __expf(-rp));
        zg = 1.f / (1.f + __expf(-zp));
        st2(rhc + ob * 512 + col, (u16)f2bf(r * hown));
      }
      tgt += 32; gbarA(bar, tgt);
      // phase 2
      pf_hc = pf_hn;
      u32x4 rl[4];
#pragma unroll
      for (int ks = 0; ks < 4; ++ks)
        rl[ks] = ld16(rhc + lan15 * 512 + kw + ks * 32 + ke8);
      issue_pf(t < 511 ? t + 1 : 511);
      asm volatile("s_waitcnt vmcnt(3)" ::: "memory");   // rl done, pf in flight
      __builtin_amdgcn_sched_barrier(0);
      f32x4 a2 = z4;
#pragma unroll
      for (int ks = 0; ks < 4; ++ks)
        a2 = MFMA16(__builtin_bit_cast(s16x8, rl[ks]), whh[ks], a2);
      *(f32x4*)(red + ROFF(wave, lan15, lanhi * 4)) = a2;
      __syncthreads();
      float hn;
      {
        float wp = upk<GXBF>(pf_hc);
#pragma unroll
        for (int w = 0; w < 4; ++w) wp += red[ROFF(w, col - c0, ob)];
        float pre = fminf(15.f, fmaxf(-15.f, wp));
        float e = __expf(-2.f * pre);
        float ht = (1.f - e) / (1.f + e);
        hn = (1.f - zg) * hown + zg * ht;
        hown = hn;
        u16 hv = (u16)f2bf(hn);
        st2(hbq + ((t + 1) & 3) * 8192 + ob * 512 + col, hv);
        st2c(ys0 + ((size_t)gb * 512 + t) * 512 + col, hv);   // cross-XCD publish
      }
      tgt += 32;
      gbarA(bar, tgt);                           // ALWAYS (t=511 too): gates prog bump
      if (tid == 0 && slot == 0)
        __hip_atomic_fetch_add(prog, 1, __ATOMIC_RELAXED, __HIP_MEMORY_SCOPE_AGENT);
      if (t == 511)
        finals[(size_t)(gb * 2 + 0) * 512 + col] = hn;
    }
  } else {
    // ================= consumer quarter (layer 1, fused input proj) =================
    s16x8 w1rz[2][4], w1h[4];
#pragma unroll
    for (int g = 0; g < 2; ++g)
#pragma unroll
      for (int ks = 0; ks < 4; ++ks)
        w1rz[g][ks] = *(const s16x8*)(WTl + ((size_t)(g * 512 + c0 + lan15)) * 1024 + kw + ks * 32 + ke8);
#pragma unroll
    for (int ks = 0; ks < 4; ++ks)
      w1h[ks] = *(const s16x8*)(WTl + ((size_t)(1024 + c0 + lan15)) * 1024 + kw + ks * 32 + ke8);
    const float brv = br[512 + col], bzv = bz[512 + col], bhv = bh[512 + col];

    u32x4 yl[4];                                 // ys0 fragments (single buffer)
    // prologue: wait producer quarter step 0, issue yl(0)
    if (tid == 0) {
      int pv, it = 0;
      do {
        pv = __hip_atomic_load(prog, __ATOMIC_RELAXED, __HIP_MEMORY_SCOPE_AGENT);
        if (pv > 0) break;
        __builtin_amdgcn_s_sleep(2);
      } while (++it < (1 << 22));
      s_prog = pv;
    }
    __syncthreads();
    __builtin_amdgcn_sched_barrier(0);
#pragma unroll
    for (int ks = 0; ks < 4; ++ks)
      yl[ks] = ld16c(ys0 + ((size_t)(q * 16 + lan15) * 512 + 0) * 512 + kw + ks * 32 + ke8);

    int tgt = 0;
    for (int t = 0; t < 512; ++t) {
      const u16* hc = hbq + (t & 3) * 8192;
      u16* rhc = rhbq + (t & 3) * 8192;
      u32x4 hl[4];
#pragma unroll
      for (int ks = 0; ks < 4; ++ks)
        hl[ks] = ld16(hc + lan15 * 512 + kw + ks * 32 + ke8);
      waitv0();                                  // hl + prefetched yl retired
      // phase 1: r-gate, z-gate, AND ys0@W1h (3 blocks of 16 cols)
      f32x4 a0 = z4, a1 = z4, a2 = z4;
#pragma unroll
      for (int ks = 0; ks < 4; ++ks) {
        s16x8 ah = __builtin_bit_cast(s16x8, hl[ks]);
        s16x8 ay = __builtin_bit_cast(s16x8, yl[ks]);
        a0 = MFMA16(ah, wrz[0][ks], a0);
        a0 = MFMA16(ay, w1rz[0][ks], a0);
        a1 = MFMA16(ah, wrz[1][ks], a1);
        a1 = MFMA16(ay, w1rz[1][ks], a1);
        a2 = MFMA16(ay, w1h[ks], a2);
      }
      *(f32x4*)(red + ROFF(wave, lan15, lanhi * 4)) = a0;
      *(f32x4*)(red + ROFF(wave, 16 + lan15, lanhi * 4)) = a1;
      *(f32x4*)(red + ROFF(wave, 32 + lan15, lanhi * 4)) = a2;
      __syncthreads();
      float zg, w1c;
      {
        float rp = brv, zp = bzv, wc = 0.f;
#pragma unroll
        for (int w = 0; w < 4; ++w) {
          rp += red[ROFF(w, col - c0, ob)];
          zp += red[ROFF(w, 16 + (col - c0), ob)];
          wc += red[ROFF(w, 32 + (col - c0), ob)];
        }
        float r = 1.f / (1.f + __expf(-rp));
        zg = 1.f / (1.f + __expf(-zp));
        w1c = wc;
        st2(rhc + ob * 512 + col, (u16)f2bf(r * hown));
      }
      // barrier 1 split: arrive -> (prog check + yl(t+1) issue) -> wait
      tgt += 32;
      bar_arrive(bar);
      if (t != 511) {
        if (s_prog < t + 2) {
          if (tid == 0) {
            int pv, it = 0;
            do {
              pv = __hip_atomic_load(prog, __ATOMIC_RELAXED, __HIP_MEMORY_SCOPE_AGENT);
              if (pv >= t + 2) break;
              __builtin_amdgcn_s_sleep(2);
            } while (++it < (1 << 22));
            s_prog = pv;
          }
          __syncthreads();
        }
#pragma unroll
        for (int ks = 0; ks < 4; ++ks)
          yl[ks] = ld16c(ys0 + ((size_t)(q * 16 + lan15) * 512 + (t + 1)) * 512 + kw + ks * 32 + ke8);
      }
      bar_wait(bar, tgt);
      // phase 2: (r*h)@Whh only (yl's W1h term came via red block 2)
      u32x4 rl[4];
#pragma unroll
      for (int ks = 0; ks < 4; ++ks)
        rl[ks] = ld16(rhc + lan15 * 512 + kw + ks * 32 + ke8);
      waitv0();                                  // drains rl AND yl(t+1) prefetch
      f32x4 a3 = z4;
#pragma unroll
      for (int ks = 0; ks < 4; ++ks)
        a3 = MFMA16(__builtin_bit_cast(s16x8, rl[ks]), whh[ks], a3);
      *(f32x4*)(red + ROFF(wave, lan15, lanhi * 4)) = a3;
      __syncthreads();
      float hn;
      {
        float wp = bhv + w1c;
#pragma unroll
        for (int w = 0; w < 4; ++w) wp += red[ROFF(w, col - c0, ob)];
        float pre = fminf(15.f, fmaxf(-15.f, wp));
        float e = __expf(-2.f * pre);
        float ht = (1.f - e) / (1.f + e);
        hn = (1.f - zg) * hown + zg * ht;
        hown = hn;
        st2(hbq + ((t + 1) & 3) * 8192 + ob * 512 + col, (u16)f2bf(hn));
      }
      // barrier 2 split: arrive -> output store -> wait
      tgt += 32;
      if (t != 511) {
        bar_arrive(bar);
        st4(out_f32 + ((size_t)gb * 512 + t) * 512 + col, __builtin_bit_cast(uint, hn));
        bar_wait(bar, tgt);
      } else {
        st4(out_f32 + ((size_t)gb * 512 + t) * 512 + col, __builtin_bit_cast(uint, hn));
        finals[(size_t)(gb * 2 + 1) * 512 + col] = hn;
      }
    }
  }
}

template <int GXBF>
static void run_all(const float* x, const float* h, const float* Wr, const float* br,
                    const float* Wz, const float* bz, const float* Wh, const float* bh,
                    float* out, char* ws, hipStream_t stream) {
  int* sync  = (int*)(ws + OFF_SYNC);
  u16* hbAll = (u16*)(ws + OFF_HB);
  u16* rhb   = (u16*)(ws + OFF_RHB);
  u16* WT    = (u16*)(ws + OFF_WT);
  u16* ys0   = (u16*)(ws + OFF_YS0);
  void* gx   = (void*)(ws + OFF_GX);
  float* finals = out + 16777216;

  init_kernel<<<64, 256, 0, stream>>>(h, hbAll, sync);
  convert_w_kernel<<<12288, 256, 0, stream>>>(Wr, Wz, Wh, WT);
  proj_kernel<GXBF><<<3072, 256, 0, stream>>>(x, WT, br, bz, bh, gx);
  gru_pipe<GXBF><<<256, 256, 0, stream>>>(gx, WT, h, hbAll, rhb, ys0,
                                          br, bz, bh, out, finals, sync);
}

extern "C" void kernel_launch(void* const* d_in, const int* in_sizes, int n_in,
                              void* d_out, int out_size, void* d_ws, size_t ws_size,
                              hipStream_t stream) {
  const float* x  = (const float*)d_in[0];
  const float* h  = (const float*)d_in[1];
  const float* Wr = (const float*)d_in[2];
  const float* br = (const float*)d_in[3];
  const float* Wz = (const float*)d_in[4];
  const float* bz = (const float*)d_in[5];
  const float* Wh = (const float*)d_in[6];
  const float* bh = (const float*)d_in[7];
  float* out = (float*)d_out;
  char* ws = (char*)d_ws;

  const size_t need_f32 = OFF_GX + GX_ELEMS * 4;   // 242,223,104 B (231.0 MiB)
  const size_t need_bf  = OFF_GX + GX_ELEMS * 2;   // 141,559,808 B (135.0 MiB)

  if (ws_size >= need_f32) {
    run_all<0>(x, h, Wr, br, Wz, bz, Wh, bh, out, ws, stream);
  } else if (ws_size >= need_bf) {
    run_all<1>(x, h, Wr, br, Wz, bz, Wh, bh, out, ws, stream);
  } else {
    sentinel_kernel<<<1, 64, 0, stream>>>(out, (float)ws_size);
  }
}